// Round 9
// baseline (1464.205 us; speedup 1.0000x reference)
//
#include <hip/hip_runtime.h>
#include <hip/hip_bf16.h>

#define NB 131072
#define MARGINF 5e-7f
#define CMARGINF 4e-4f
// ws layout: doubles[128] at float idx 0..255 (vq slots 0..63, rec slots 64..127);
// e2[512] at float idx 256..767; bitmask u32[4096] at word idx 768..4863;
// bf16 split-weight region from float idx 4864.
#define WS_E2 256
#define WS_MASK 768
#define WS_MASKW 4096
#define WS_BASE_BYTES ((768 + 4096) * 4)
#define WS_SPLIT_F 4864
// split region offsets (bf16 element units, relative to split base)
#define OFF_W2 0
#define OFF_W3 131072
#define OFF_EMB 196608
#define OFF_D1 327680
#define OFF_D2 393216
#define OFF_RW 524288
#define SPLIT_TOTAL 532480

typedef __attribute__((ext_vector_type(8))) short short8v;
typedef __attribute__((ext_vector_type(4))) float f32x4;
typedef __attribute__((ext_vector_type(4))) unsigned short ushort4v;

#define SWC(j) ((((j) >> 2) & 7) << 2)

__device__ __forceinline__ unsigned short bf16rn(float x) {
    unsigned u = __float_as_uint(x);
    unsigned r = u + 0x7fffu + ((u >> 16) & 1u);
    return (unsigned short)(r >> 16);
}
__device__ __forceinline__ void split2(float x, unsigned short& h, unsigned short& l) {
    h = bf16rn(x);
    float hf = __uint_as_float((unsigned)h << 16);
    l = bf16rn(x - hf);
}

// ---------------- prep: zero accum/mask + e2 + fragment-linear bf16 splits ----------------
__global__ void prep_kernel(
    const float* __restrict__ w2, const float* __restrict__ w3,
    const float* __restrict__ emb, const float* __restrict__ d1w,
    const float* __restrict__ d2w, const float* __restrict__ rw,
    float* __restrict__ ws, int do_splits)
{
    const int gid = blockIdx.x * 256 + threadIdx.x;
    const int stride = gridDim.x * 256;
    // zero loss slots (float idx 0..255) and flag mask (768..4863)
    for (int z = gid; z < 4352; z += stride) {
        int a = (z < 256) ? z : (512 + z);
        ws[a] = 0.f;
    }
    const int total = 512 + 266240;
    unsigned short* wsb = (unsigned short*)(ws + WS_SPLIT_F);
    for (int idx = gid; idx < total; idx += stride) {
        if (idx < 512) {
            const float* e = emb + (size_t)idx * 128;
            float s0 = 0.f, s1 = 0.f, s2 = 0.f, s3 = 0.f;
            for (int d = 0; d < 128; d += 4) {
                s0 += e[d] * e[d];     s1 += e[d + 1] * e[d + 1];
                s2 += e[d + 2] * e[d + 2]; s3 += e[d + 3] * e[d + 3];
            }
            ws[WS_E2 + idx] = (s0 + s1) + (s2 + s3);
            continue;
        }
        if (!do_splits) continue;
        int j = idx - 512;
        int base, K, o, k;
        float src;
        bool wlo;
        if (j < 65536) {            // w2: 256x256 (3-term consumer: lo needed)
            o = j >> 8; k = j & 255; base = OFF_W2; K = 256; src = w2[o * 256 + k]; wlo = true;
        } else if (j < 98304) {     // w3: 128x256 (3-term consumer)
            j -= 65536; o = j >> 8; k = j & 255; base = OFF_W3; K = 256; src = w3[o * 256 + k]; wlo = true;
        } else if (j < 163840) {    // emb: 512x128 (coarse hi-only consumer)
            j -= 98304; o = j >> 7; k = j & 127; base = OFF_EMB; K = 128; src = emb[o * 128 + k]; wlo = false;
        } else if (j < 196608) {    // d1w: 256x128 (hi-only)
            j -= 163840; o = j >> 7; k = j & 127; base = OFF_D1; K = 128; src = d1w[o * 128 + k]; wlo = false;
        } else if (j < 262144) {    // d2w: 256x256 (hi-only)
            j -= 196608; o = j >> 8; k = j & 255; base = OFF_D2; K = 256; src = d2w[o * 256 + k]; wlo = false;
        } else {                    // rw padded to 16 rows: 16x256 (hi-only)
            j -= 262144; o = j >> 8; k = j & 255; base = OFF_RW; K = 256;
            src = (o < 6) ? rw[o * 256 + k] : 0.f; wlo = false;
        }
        unsigned short h, l;
        split2(src, h, l);
        int jt = o >> 4, c = k >> 5;
        int lane = (((k >> 3) & 3) << 4) | (o & 15);
        int e = k & 7;
        int a = base + ((jt * (K >> 5) + c) * 2) * 512 + lane * 8 + e;
        wsb[a] = h;
        if (wlo) wsb[a + 512] = l;
    }
}

// ---------------- MFMA main kernel: 64 rows/block, 4 waves ----------------
// Activations hi/lo bf16 in dynamic LDS [64 rows][264]. Weight frags from ws (L2).
// TERMS=3: error-compensated. TERMS=1: hi-only. WRITELO: store lo split of outputs.

template<int NJT, int KC, bool RELU, bool SQSUM, int TERMS, bool WRITELO>
__device__ __forceinline__ void mfma_mlp4(
    const short8v* __restrict__ Wf, const float* __restrict__ bias,
    unsigned short* HHp, unsigned short* HLp, float* ENC2Wp,
    int w, int lane)
{
    const int lc = lane & 15, lg = lane >> 4;
    f32x4 acc[NJT][4];
#pragma unroll
    for (int jj = 0; jj < NJT; ++jj)
#pragma unroll
        for (int rt = 0; rt < 4; ++rt)
            acc[jj][rt] = (f32x4){0.f, 0.f, 0.f, 0.f};

    __syncthreads();  // inputs ready
    for (int c = 0; c < KC; ++c) {
        const int boff = c * 32 + lg * 8;
        short8v bh[4], bl[4];
#pragma unroll
        for (int rt = 0; rt < 4; ++rt) {
            bh[rt] = *(const short8v*)&HHp[(rt * 16 + lc) * 264 + boff];
            if (TERMS == 3)
                bl[rt] = *(const short8v*)&HLp[(rt * 16 + lc) * 264 + boff];
        }
#pragma unroll
        for (int jj = 0; jj < NJT; ++jj) {
            int fi = (((w * NJT + jj) * KC + c) * 2) * 64 + lane;
            short8v ah = Wf[fi];
            if (TERMS == 3) {
                short8v al = Wf[fi + 64];
#pragma unroll
                for (int rt = 0; rt < 4; ++rt) {
                    acc[jj][rt] = __builtin_amdgcn_mfma_f32_16x16x32_bf16(al, bh[rt], acc[jj][rt], 0, 0, 0);
                    acc[jj][rt] = __builtin_amdgcn_mfma_f32_16x16x32_bf16(ah, bl[rt], acc[jj][rt], 0, 0, 0);
                    acc[jj][rt] = __builtin_amdgcn_mfma_f32_16x16x32_bf16(ah, bh[rt], acc[jj][rt], 0, 0, 0);
                }
            } else {
#pragma unroll
                for (int rt = 0; rt < 4; ++rt)
                    acc[jj][rt] = __builtin_amdgcn_mfma_f32_16x16x32_bf16(ah, bh[rt], acc[jj][rt], 0, 0, 0);
            }
        }
    }
    __syncthreads();  // all reads done; in-place writes now safe

    float sq[4] = {0.f, 0.f, 0.f, 0.f};
#pragma unroll
    for (int jj = 0; jj < NJT; ++jj) {
        int j0 = (w * NJT + jj) * 16 + lg * 4;
        float4 bv = *(const float4*)&bias[j0];
        float bb[4] = {bv.x, bv.y, bv.z, bv.w};
#pragma unroll
        for (int rt = 0; rt < 4; ++rt) {
            int r = rt * 16 + lc;
            ushort4v hv, lv;
#pragma unroll
            for (int reg = 0; reg < 4; ++reg) {
                float v = acc[jj][rt][reg] + bb[reg];
                if (RELU) v = fmaxf(v, 0.f);
                if (SQSUM) sq[rt] += v * v;
                if (WRITELO) {
                    unsigned short h, l;
                    split2(v, h, l);
                    hv[reg] = h; lv[reg] = l;
                } else {
                    hv[reg] = bf16rn(v);
                }
            }
            *(ushort4v*)&HHp[r * 264 + j0] = hv;
            if (WRITELO) *(ushort4v*)&HLp[r * 264 + j0] = lv;
        }
    }
    if (SQSUM) {
#pragma unroll
        for (int rt = 0; rt < 4; ++rt) {
            float s = sq[rt];
            s += __shfl_xor(s, 16);
            s += __shfl_xor(s, 32);
            if (lg == 0) ENC2Wp[w * 64 + rt * 16 + lc] = s;
        }
    }
}

__global__ __launch_bounds__(256, 2) void vqvae_main_mfma(
    const float* __restrict__ action,
    const float* __restrict__ w1, const float* __restrict__ b1,
    const float* __restrict__ b2, const float* __restrict__ b3,
    const float* __restrict__ emb,
    const float* __restrict__ d1b, const float* __restrict__ d2b,
    const float* __restrict__ rb,
    float* __restrict__ out, float* __restrict__ ws)
{
    extern __shared__ __align__(16) unsigned short DYN[];
    unsigned short* HH = DYN;              // [64][264]
    unsigned short* HL = DYN + 64 * 264;   // [64][264]

    __shared__ float AT[64 * 6];
    __shared__ float E2S[512];
    __shared__ float ENC2W[4 * 64];
    __shared__ float WMIN[4][64];
    __shared__ float CMIN[64];
    __shared__ unsigned int CAND[64 * 16];
    __shared__ int IDXR[64];
    __shared__ int FLAGR[64];
    __shared__ float RED[8];

    const int t = threadIdx.x;
    const int w = t >> 6, lane = t & 63;
    const int lc = lane & 15, lg = lane >> 4;
    const int row0 = blockIdx.x * 64;
    const unsigned short* wsb = (const unsigned short*)(ws + WS_SPLIT_F);
    const short8v* W2f = (const short8v*)wsb + OFF_W2 / 8;
    const short8v* W3f = (const short8v*)wsb + OFF_W3 / 8;
    const short8v* EMBf = (const short8v*)wsb + OFF_EMB / 8;
    const short8v* D1f = (const short8v*)wsb + OFF_D1 / 8;
    const short8v* D2f = (const short8v*)wsb + OFF_D2 / 8;
    const short8v* RWf = (const short8v*)wsb + OFF_RW / 8;

    // ---- stage action (row-major [r][6]) + e2 ----
    for (int i = t; i < 384; i += 256) AT[i] = action[(size_t)row0 * 6 + i];
    for (int i = t; i < 512; i += 256) E2S[i] = ws[WS_E2 + i];
    __syncthreads();

    // ---- enc1 (VALU fp32): h1[j=t][r=0..63] -> splits ----
    {
        float wr[6];
#pragma unroll
        for (int i = 0; i < 6; ++i) wr[i] = w1[t * 6 + i];
        float bb = b1[t];
        for (int r = 0; r < 64; ++r) {
            float s = bb;
#pragma unroll
            for (int i = 0; i < 6; ++i) s += wr[i] * AT[r * 6 + i];
            s = fmaxf(s, 0.f);
            unsigned short h, l;
            split2(s, h, l);
            HH[r * 264 + t] = h;
            HL[r * 264 + t] = l;
        }
    }

    // ---- enc2: 256 -> 256 relu (3-term) ----
    mfma_mlp4<4, 8, true, false, 3, true>(W2f, b2, HH, HL, ENC2W, w, lane);
    // ---- mu: 256 -> 128, no relu, + per-row ||enc||^2 (3-term, hi/lo out) ----
    mfma_mlp4<2, 8, false, true, 3, true>(W3f, b3, HH, HL, ENC2W, w, lane);

    // ---- VQ stage 1, sweep A: coarse row-min via hi-only MFMA (register-light) ----
    float lvq = 0.f, lrec = 0.f;
    {
        for (int i = t; i < 1024; i += 256) CAND[i] = 0u;
        float v1[4][4];
#pragma unroll
        for (int rt = 0; rt < 4; ++rt)
#pragma unroll
            for (int reg = 0; reg < 4; ++reg) v1[rt][reg] = 1e30f;
        __syncthreads();  // enc splits + CAND zero ready
        for (int p = 0; p < 2; ++p) {
            f32x4 vacc[4][4];
#pragma unroll
            for (int kt = 0; kt < 4; ++kt)
#pragma unroll
                for (int rt = 0; rt < 4; ++rt)
                    vacc[kt][rt] = (f32x4){0.f, 0.f, 0.f, 0.f};
            for (int c = 0; c < 4; ++c) {
                const int aoff = c * 32 + lg * 8;
                short8v ah[4];
#pragma unroll
                for (int rt = 0; rt < 4; ++rt)
                    ah[rt] = *(const short8v*)&HH[(rt * 16 + lc) * 264 + aoff];
#pragma unroll
                for (int kt = 0; kt < 4; ++kt) {
                    int ktg = w * 8 + p * 4 + kt;
                    short8v bh = EMBf[((ktg * 4 + c) * 2) * 64 + lane];
#pragma unroll
                    for (int rt = 0; rt < 4; ++rt)
                        vacc[kt][rt] = __builtin_amdgcn_mfma_f32_16x16x32_bf16(ah[rt], bh, vacc[kt][rt], 0, 0, 0);
                }
            }
            // fold into running min, then DISCARD vacc (no long-lived accumulators)
#pragma unroll
            for (int kt = 0; kt < 4; ++kt) {
                int k = (w * 8 + p * 4 + kt) * 16 + lc;
                float ek = E2S[k];
#pragma unroll
                for (int rt = 0; rt < 4; ++rt)
#pragma unroll
                    for (int reg = 0; reg < 4; ++reg)
                        v1[rt][reg] = fminf(v1[rt][reg], ek - 2.f * vacc[kt][rt][reg]);
            }
        }
        // lane-merge min across the 16 lc lanes
#pragma unroll
        for (int m = 1; m < 16; m <<= 1)
#pragma unroll
            for (int rt = 0; rt < 4; ++rt)
#pragma unroll
                for (int reg = 0; reg < 4; ++reg)
                    v1[rt][reg] = fminf(v1[rt][reg], __shfl_xor(v1[rt][reg], m));
        if (lc == 0) {
#pragma unroll
            for (int rt = 0; rt < 4; ++rt)
#pragma unroll
                for (int reg = 0; reg < 4; ++reg)
                    WMIN[w][rt * 16 + lg * 4 + reg] = v1[rt][reg];
        }
        __syncthreads();
        if (t < 64)
            CMIN[t] = fminf(fminf(WMIN[0][t], WMIN[1][t]), fminf(WMIN[2][t], WMIN[3][t]));
        __syncthreads();

        // ---- sweep B: recompute coarse dd, collect candidates within window ----
        for (int p = 0; p < 2; ++p) {
            f32x4 vacc[4][4];
#pragma unroll
            for (int kt = 0; kt < 4; ++kt)
#pragma unroll
                for (int rt = 0; rt < 4; ++rt)
                    vacc[kt][rt] = (f32x4){0.f, 0.f, 0.f, 0.f};
            for (int c = 0; c < 4; ++c) {
                const int aoff = c * 32 + lg * 8;
                short8v ah[4];
#pragma unroll
                for (int rt = 0; rt < 4; ++rt)
                    ah[rt] = *(const short8v*)&HH[(rt * 16 + lc) * 264 + aoff];
#pragma unroll
                for (int kt = 0; kt < 4; ++kt) {
                    int ktg = w * 8 + p * 4 + kt;
                    short8v bh = EMBf[((ktg * 4 + c) * 2) * 64 + lane];
#pragma unroll
                    for (int rt = 0; rt < 4; ++rt)
                        vacc[kt][rt] = __builtin_amdgcn_mfma_f32_16x16x32_bf16(ah[rt], bh, vacc[kt][rt], 0, 0, 0);
                }
            }
#pragma unroll
            for (int kt = 0; kt < 4; ++kt) {
                int k = (w * 8 + p * 4 + kt) * 16 + lc;
                float ek = E2S[k];
#pragma unroll
                for (int rt = 0; rt < 4; ++rt)
#pragma unroll
                    for (int reg = 0; reg < 4; ++reg) {
                        int row = rt * 16 + lg * 4 + reg;
                        float dd = ek - 2.f * vacc[kt][rt][reg];
                        if (!(dd > CMIN[row] + CMARGINF))  // NaN-safe: NaN -> candidate
                            atomicOr(&CAND[row * 16 + (k >> 5)], 1u << (k & 31));
                    }
            }
        }
    }
    __syncthreads();

    // ---- VQ stage 2: exact fp32 rescore of candidates; idx, flag, lvq ----
    if (t < 64) {
        const int row = t;
        float v1 = 1e30f, v2 = 1e30f; int k1 = 0;
        for (int wd = 0; wd < 16; ++wd) {
            unsigned int m = CAND[row * 16 + wd];
            while (m) {
                int b = __ffs(m) - 1; m &= m - 1;
                int k = wd * 32 + b;
                const float* ek = emb + (size_t)k * 128;
                float s0 = 0.f, s1 = 0.f;
                for (int d = 0; d < 128; d += 2) {
                    float e0 = __uint_as_float((unsigned)HH[row * 264 + d] << 16)
                             + __uint_as_float((unsigned)HL[row * 264 + d] << 16);
                    float e1 = __uint_as_float((unsigned)HH[row * 264 + d + 1] << 16)
                             + __uint_as_float((unsigned)HL[row * 264 + d + 1] << 16);
                    s0 += e0 * ek[d];
                    s1 += e1 * ek[d + 1];
                }
                float dd = E2S[k] - 2.f * (s0 + s1);
                if (dd < v1) { v2 = v1; v1 = dd; k1 = k; }
                else if (dd < v2) v2 = dd;
            }
        }
        int flag = (v2 - v1 >= MARGINF) ? 0 : 1;  // NaN-safe
        IDXR[row] = k1;
        FLAGR[row] = flag;
        int grow = row0 + row;
        if (flag)
            atomicOr((unsigned int*)ws + WS_MASK + (grow >> 5), 1u << (grow & 31));
        out[grow] = (float)k1;
        if (!flag) {
            float enc2 = ENC2W[0 * 64 + row] + ENC2W[1 * 64 + row] +
                         ENC2W[2 * 64 + row] + ENC2W[3 * 64 + row];
            lvq = enc2 + v1;
        }
    }
    __syncthreads();

    // ---- gather q (exact fp32), write q_st, hi-only split for decoder ----
    {
        int d = t & 127, rhalf = t >> 7;
#pragma unroll
        for (int e = 0; e < 32; ++e) {
            int r = (e << 1) | rhalf;
            int k1 = IDXR[r];
            float q = emb[(size_t)k1 * 128 + d];
            out[NB + (size_t)(row0 + r) * 128 + d] = q;
            HH[r * 264 + d] = bf16rn(q);
        }
    }

    // ---- decoder (hi-only, 1-term) ----
    mfma_mlp4<4, 4, true, false, 1, false>(D1f, d1b, HH, HL, ENC2W, w, lane);
    mfma_mlp4<4, 8, true, false, 1, false>(D2f, d2b, HH, HL, ENC2W, w, lane);
    __syncthreads();  // dec2 hi ready

    // ---- rec: wave w handles rows w*16..+15 via MFMA (hi-only) ----
    {
        f32x4 racc = (f32x4){0.f, 0.f, 0.f, 0.f};
        for (int c = 0; c < 8; ++c) {
            const int boff = c * 32 + lg * 8;
            short8v bh = *(const short8v*)&HH[(w * 16 + lc) * 264 + boff];
            int fi = (c * 2) * 64 + lane;
            short8v ah = RWf[fi];
            racc = __builtin_amdgcn_mfma_f32_16x16x32_bf16(ah, bh, racc, 0, 0, 0);
        }
        int r = w * 16 + lc;
#pragma unroll
        for (int reg = 0; reg < 4; ++reg) {
            int j = lg * 4 + reg;
            if (j < 6) {
                float rec = tanhf(racc[reg] + rb[j]);
                float df = rec - AT[r * 6 + j];
                if (!FLAGR[r]) lrec += df * df;
            }
        }
    }

    // ---- block loss reduction -> hashed fp64 slots ----
#pragma unroll
    for (int m = 1; m < 64; m <<= 1) {
        lvq += __shfl_xor(lvq, m);
        lrec += __shfl_xor(lrec, m);
    }
    if ((t & 63) == 0) { RED[t >> 6] = lvq; RED[4 + (t >> 6)] = lrec; }
    __syncthreads();
    if (t == 0) {
        int slot = blockIdx.x & 63;
        atomicAdd((double*)ws + slot, (double)((RED[0] + RED[1]) + (RED[2] + RED[3])));
        atomicAdd((double*)ws + 64 + slot, (double)((RED[4] + RED[5]) + (RED[6] + RED[7])));
    }
}

// ---------------- fp64 repair of ambiguous rows (256 blocks, stride over words) ----------------
__global__ __launch_bounds__(256) void vqvae_fix(
    const float* __restrict__ action,
    const float* __restrict__ w1, const float* __restrict__ b1,
    const float* __restrict__ w2, const float* __restrict__ b2,
    const float* __restrict__ w3, const float* __restrict__ b3,
    const float* __restrict__ emb,
    const float* __restrict__ d1w, const float* __restrict__ d1b,
    const float* __restrict__ d2w, const float* __restrict__ d2b,
    const float* __restrict__ rw, const float* __restrict__ rb,
    float* __restrict__ out, float* __restrict__ ws)
{
    __shared__ double H1[256];
    __shared__ double H2[256];
    __shared__ double ENC[128];
    __shared__ double QD[128];
    __shared__ double SRED[256];
    __shared__ int SK[256];
    __shared__ double SA[6];

    const int t = threadIdx.x;

    for (int widx = blockIdx.x; widx < WS_MASKW; widx += gridDim.x) {
        const unsigned int word = ((const unsigned int*)ws)[WS_MASK + widx];
        if (word == 0u) continue;  // uniform across block

        for (int bit = 0; bit < 32; ++bit) {
            if (!(word & (1u << bit))) continue;
            const int row = (widx << 5) + bit;

            if (t < 6) SA[t] = (double)action[(size_t)row * 6 + t];
            __syncthreads();
            {
                double a = (double)b1[t];
#pragma unroll
                for (int i = 0; i < 6; ++i) a += (double)w1[t * 6 + i] * SA[i];
                H1[t] = a > 0.0 ? a : 0.0;
            }
            __syncthreads();
            {
                const float* w = w2 + (size_t)t * 256;
                double a0 = 0, a1 = 0, a2 = 0, a3 = 0;
                for (int i = 0; i < 256; i += 4) {
                    a0 += (double)w[i] * H1[i];     a1 += (double)w[i + 1] * H1[i + 1];
                    a2 += (double)w[i + 2] * H1[i + 2]; a3 += (double)w[i + 3] * H1[i + 3];
                }
                double a = (double)b2[t] + a0 + a1 + a2 + a3;
                H2[t] = a > 0.0 ? a : 0.0;
            }
            __syncthreads();
            if (t < 128) {
                const float* w = w3 + (size_t)t * 256;
                double a0 = 0, a1 = 0, a2 = 0, a3 = 0;
                for (int i = 0; i < 256; i += 4) {
                    a0 += (double)w[i] * H2[i];     a1 += (double)w[i + 1] * H2[i + 1];
                    a2 += (double)w[i + 2] * H2[i + 2]; a3 += (double)w[i + 3] * H2[i + 3];
                }
                ENC[t] = (double)b3[t] + a0 + a1 + a2 + a3;
            }
            __syncthreads();
            double best = 1e300; int bk = 0;
#pragma unroll
            for (int kk = 0; kk < 2; ++kk) {
                int k = t + kk * 256;
                const float* e = emb + (size_t)k * 128;
                double s0 = 0, s1 = 0;
                for (int d = 0; d < 128; d += 2) {
                    double df0 = ENC[d] - (double)e[d];
                    double df1 = ENC[d + 1] - (double)e[d + 1];
                    s0 += df0 * df0; s1 += df1 * df1;
                }
                double s = s0 + s1;
                if (s < best) { best = s; bk = k; }
            }
            SRED[t] = best; SK[t] = bk;
            __syncthreads();
            for (int st = 128; st > 0; st >>= 1) {
                if (t < st) {
                    double ov = SRED[t + st]; int ok = SK[t + st];
                    if (ov < SRED[t] || (ov == SRED[t] && ok < SK[t])) { SRED[t] = ov; SK[t] = ok; }
                }
                __syncthreads();
            }
            const int bestk = SK[0];
            double lv = 0.0;
            if (t < 128) {
                double q = (double)emb[(size_t)bestk * 128 + t];
                QD[t] = q;
                double df = ENC[t] - q;
                lv = df * df;
                out[NB + (size_t)row * 128 + t] = (float)q;
            }
            if (t == 0) out[row] = (float)bestk;
            __syncthreads();
            {
                const float* w = d1w + (size_t)t * 128;
                double a0 = 0, a1 = 0;
                for (int i = 0; i < 128; i += 2) {
                    a0 += (double)w[i] * QD[i]; a1 += (double)w[i + 1] * QD[i + 1];
                }
                double a = (double)d1b[t] + a0 + a1;
                H1[t] = a > 0.0 ? a : 0.0;
            }
            __syncthreads();
            {
                const float* w = d2w + (size_t)t * 256;
                double a0 = 0, a1 = 0, a2 = 0, a3 = 0;
                for (int i = 0; i < 256; i += 4) {
                    a0 += (double)w[i] * H1[i];     a1 += (double)w[i + 1] * H1[i + 1];
                    a2 += (double)w[i + 2] * H1[i + 2]; a3 += (double)w[i + 3] * H1[i + 3];
                }
                double a = (double)d2b[t] + a0 + a1 + a2 + a3;
                H2[t] = a > 0.0 ? a : 0.0;
            }
            __syncthreads();
            double lr = 0.0;
            if (t < 6) {
                const float* w = rw + (size_t)t * 256;
                double a0 = 0, a1 = 0;
                for (int i = 0; i < 256; i += 2) {
                    a0 += (double)w[i] * H2[i]; a1 += (double)w[i + 1] * H2[i + 1];
                }
                double rec = tanh((double)rb[t] + a0 + a1);
                double df = rec - SA[t];
                lr = df * df;
            }
            SRED[t] = lv;
            __syncthreads();
            for (int st = 128; st > 0; st >>= 1) {
                if (t < st) SRED[t] += SRED[t + st];
                __syncthreads();
            }
            if (t == 0) atomicAdd((double*)ws + 0, SRED[0]);
            if (t < 6) atomicAdd((double*)ws + 64, lr);
            __syncthreads();
        }
    }
}

__global__ void vqvae_fin(const float* __restrict__ ws, float* __restrict__ out) {
    if (threadIdx.x == 0 && blockIdx.x == 0) {
        const double* D = (const double*)ws;
        double sv = 0.0, sr = 0.0;
        for (int i = 0; i < 64; ++i) { sv += D[i]; sr += D[64 + i]; }
        double loss = sr / ((double)NB * 6.0) + 1.25 * (sv / ((double)NB * 128.0));
        out[(size_t)NB * 129] = (float)loss;
    }
}

// ---------------- fp32 fallback (only if ws too small for splits) ----------------
static __device__ __forceinline__ void gemm_out256(
    const float* __restrict__ W, const float* __restrict__ bias, int IN,
    const float* __restrict__ hin, float* __restrict__ hout,
    float* __restrict__ WC, int t, int tx, int r0, bool do_relu)
{
    float acc[2][4][4];
#pragma unroll
    for (int g = 0; g < 2; ++g)
#pragma unroll
        for (int a = 0; a < 4; ++a)
#pragma unroll
            for (int b = 0; b < 4; ++b) acc[g][a][b] = 0.f;
    float4 pa = *(const float4*)(W + (size_t)t * IN);
    float4 pb = *(const float4*)(W + (size_t)t * IN + 4);
    for (int i0 = 0; i0 < IN; i0 += 8) {
        __syncthreads();
        WC[0 * 256 + t] = pa.x; WC[1 * 256 + t] = pa.y;
        WC[2 * 256 + t] = pa.z; WC[3 * 256 + t] = pa.w;
        WC[4 * 256 + t] = pb.x; WC[5 * 256 + t] = pb.y;
        WC[6 * 256 + t] = pb.z; WC[7 * 256 + t] = pb.w;
        __syncthreads();
        if (i0 + 8 < IN) {
            pa = *(const float4*)(W + (size_t)t * IN + i0 + 8);
            pb = *(const float4*)(W + (size_t)t * IN + i0 + 12);
        }
#pragma unroll
        for (int i = 0; i < 8; ++i) {
            int row = i0 + i;
            float4 h = *(const float4*)&hin[row * 32 + (r0 ^ SWC(row))];
            float4 w0 = *(const float4*)&WC[i * 256 + 4 * tx];
            float4 w1v = *(const float4*)&WC[i * 256 + 128 + 4 * tx];
            float wv0[4] = {w0.x, w0.y, w0.z, w0.w};
            float wv1[4] = {w1v.x, w1v.y, w1v.z, w1v.w};
            float hv[4] = {h.x, h.y, h.z, h.w};
#pragma unroll
            for (int a = 0; a < 4; ++a)
#pragma unroll
                for (int b = 0; b < 4; ++b) {
                    acc[0][a][b] += wv0[a] * hv[b];
                    acc[1][a][b] += wv1[a] * hv[b];
                }
        }
    }
#pragma unroll
    for (int g = 0; g < 2; ++g)
#pragma unroll
        for (int a = 0; a < 4; ++a) {
            int j = g * 128 + 4 * tx + a;
            float bj = bias[j];
            float4 v;
            v.x = acc[g][a][0] + bj; v.y = acc[g][a][1] + bj;
            v.z = acc[g][a][2] + bj; v.w = acc[g][a][3] + bj;
            if (do_relu) {
                v.x = fmaxf(v.x, 0.f); v.y = fmaxf(v.y, 0.f);
                v.z = fmaxf(v.z, 0.f); v.w = fmaxf(v.w, 0.f);
            }
            *(float4*)&hout[j * 32 + (r0 ^ SWC(j))] = v;
        }
    __syncthreads();
}

__global__ __launch_bounds__(256, 2) void vqvae_main_fp32(
    const float* __restrict__ action,
    const float* __restrict__ w1, const float* __restrict__ b1,
    const float* __restrict__ w2, const float* __restrict__ b2,
    const float* __restrict__ w3, const float* __restrict__ b3,
    const float* __restrict__ emb,
    const float* __restrict__ d1w, const float* __restrict__ d1b,
    const float* __restrict__ d2w, const float* __restrict__ d2b,
    const float* __restrict__ rw, const float* __restrict__ rb,
    float* __restrict__ out, float* __restrict__ ws)
{
    __shared__ float X[256 * 32];
    __shared__ float Y[256 * 32];
    __shared__ float WC[2048];
    __shared__ float AT[6 * 32];
    __shared__ int IDXR[32];
    __shared__ int FLAGR[32];
    __shared__ float RED[8];

    const int t = threadIdx.x;
    const int tx = t & 31, ty = t >> 5;
    const int r0 = ty * 4;
    const int row0 = blockIdx.x * 32;

    if (t < 192) {
        int r = t / 6, i = t - r * 6;
        AT[i * 32 + r] = action[(size_t)row0 * 6 + t];
    }
    __syncthreads();
    {
#pragma unroll
        for (int i = 0; i < 6; ++i) WC[i * 256 + t] = w1[t * 6 + i];
        __syncthreads();
        float acc[2][4][4];
#pragma unroll
        for (int g = 0; g < 2; ++g)
#pragma unroll
            for (int a = 0; a < 4; ++a)
#pragma unroll
                for (int b = 0; b < 4; ++b) acc[g][a][b] = 0.f;
#pragma unroll
        for (int i = 0; i < 6; ++i) {
            float4 h = *(const float4*)&AT[i * 32 + r0];
            float4 w0 = *(const float4*)&WC[i * 256 + 4 * tx];
            float4 w1v = *(const float4*)&WC[i * 256 + 128 + 4 * tx];
            float wv0[4] = {w0.x, w0.y, w0.z, w0.w};
            float wv1[4] = {w1v.x, w1v.y, w1v.z, w1v.w};
            float hv[4] = {h.x, h.y, h.z, h.w};
#pragma unroll
            for (int a = 0; a < 4; ++a)
#pragma unroll
                for (int b = 0; b < 4; ++b) {
                    acc[0][a][b] += wv0[a] * hv[b];
                    acc[1][a][b] += wv1[a] * hv[b];
                }
        }
#pragma unroll
        for (int g = 0; g < 2; ++g)
#pragma unroll
            for (int a = 0; a < 4; ++a) {
                int j = g * 128 + 4 * tx + a;
                float bj = b1[j];
                float4 v;
                v.x = fmaxf(acc[g][a][0] + bj, 0.f);
                v.y = fmaxf(acc[g][a][1] + bj, 0.f);
                v.z = fmaxf(acc[g][a][2] + bj, 0.f);
                v.w = fmaxf(acc[g][a][3] + bj, 0.f);
                *(float4*)&X[j * 32 + (r0 ^ SWC(j))] = v;
            }
        __syncthreads();
    }
    gemm_out256(w2, b2, 256, X, Y, WC, t, tx, r0, true);
    {
        float acc[4][4];
#pragma unroll
        for (int a = 0; a < 4; ++a)
#pragma unroll
            for (int b = 0; b < 4; ++b) acc[a][b] = 0.f;
        float4 pa, pb;
        if (t < 128) {
            pa = *(const float4*)(w3 + (size_t)t * 256);
            pb = *(const float4*)(w3 + (size_t)t * 256 + 4);
        }
        for (int i0 = 0; i0 < 256; i0 += 8) {
            __syncthreads();
            if (t < 128) {
                WC[0 * 128 + t] = pa.x; WC[1 * 128 + t] = pa.y;
                WC[2 * 128 + t] = pa.z; WC[3 * 128 + t] = pa.w;
                WC[4 * 128 + t] = pb.x; WC[5 * 128 + t] = pb.y;
                WC[6 * 128 + t] = pb.z; WC[7 * 128 + t] = pb.w;
            }
            __syncthreads();
            if (t < 128 && i0 + 8 < 256) {
                pa = *(const float4*)(w3 + (size_t)t * 256 + i0 + 8);
                pb = *(const float4*)(w3 + (size_t)t * 256 + i0 + 12);
            }
#pragma unroll
            for (int i = 0; i < 8; ++i) {
                int row = i0 + i;
                float4 h = *(const float4*)&Y[row * 32 + (r0 ^ SWC(row))];
                float4 w0 = *(const float4*)&WC[i * 128 + 4 * tx];
                float wv[4] = {w0.x, w0.y, w0.z, w0.w};
                float hv[4] = {h.x, h.y, h.z, h.w};
#pragma unroll
                for (int a = 0; a < 4; ++a)
#pragma unroll
                    for (int b = 0; b < 4; ++b) acc[a][b] += wv[a] * hv[b];
            }
        }
#pragma unroll
        for (int a = 0; a < 4; ++a) {
            int j = 4 * tx + a;
            float bj = b3[j];
            float4 v;
            v.x = acc[a][0] + bj; v.y = acc[a][1] + bj;
            v.z = acc[a][2] + bj; v.w = acc[a][3] + bj;
            *(float4*)&X[j * 32 + (r0 ^ SWC(j))] = v;
        }
        __syncthreads();
    }
    {
        float bv1[4], bv2[4];
        int bk1[4];
        float acc[4][4][4];
#pragma unroll
        for (int p = 0; p < 4; ++p)
#pragma unroll
            for (int a = 0; a < 4; ++a)
#pragma unroll
                for (int b = 0; b < 4; ++b) acc[p][a][b] = 0.f;
        float4 qa = *(const float4*)(emb + (size_t)t * 128);
        float4 qb = *(const float4*)(emb + (size_t)(t + 256) * 128);
        for (int d0 = 0; d0 < 128; d0 += 4) {
            __syncthreads();
            WC[0 * 512 + t] = qa.x; WC[1 * 512 + t] = qa.y;
            WC[2 * 512 + t] = qa.z; WC[3 * 512 + t] = qa.w;
            WC[0 * 512 + 256 + t] = qb.x; WC[1 * 512 + 256 + t] = qb.y;
            WC[2 * 512 + 256 + t] = qb.z; WC[3 * 512 + 256 + t] = qb.w;
            __syncthreads();
            if (d0 + 4 < 128) {
                qa = *(const float4*)(emb + (size_t)t * 128 + d0 + 4);
                qb = *(const float4*)(emb + (size_t)(t + 256) * 128 + d0 + 4);
            }
#pragma unroll
            for (int i = 0; i < 4; ++i) {
                int row = d0 + i;
                float4 h = *(const float4*)&X[row * 32 + (r0 ^ SWC(row))];
                float hv[4] = {h.x, h.y, h.z, h.w};
#pragma unroll
                for (int p = 0; p < 4; ++p) {
                    float4 w0 = *(const float4*)&WC[i * 512 + p * 128 + 4 * tx];
                    float wv[4] = {w0.x, w0.y, w0.z, w0.w};
#pragma unroll
                    for (int a = 0; a < 4; ++a)
#pragma unroll
                        for (int b = 0; b < 4; ++b) acc[p][a][b] += wv[a] * hv[b];
                }
            }
        }
#pragma unroll
        for (int b = 0; b < 4; ++b) { bv1[b] = 1e30f; bv2[b] = 1e30f; bk1[b] = 0; }
#pragma unroll
        for (int p = 0; p < 4; ++p)
#pragma unroll
            for (int a = 0; a < 4; ++a) {
                int k = p * 128 + 4 * tx + a;
                float ek = ws[WS_E2 + k];
#pragma unroll
                for (int b = 0; b < 4; ++b) {
                    float dd = ek - 2.f * acc[p][a][b];
                    if (dd < bv1[b]) { bv2[b] = bv1[b]; bv1[b] = dd; bk1[b] = k; }
                    else if (dd < bv2[b]) bv2[b] = dd;
                }
            }
#pragma unroll
        for (int m = 1; m < 32; m <<= 1) {
#pragma unroll
            for (int b = 0; b < 4; ++b) {
                float ov1 = __shfl_xor(bv1[b], m);
                int ok1 = __shfl_xor(bk1[b], m);
                float ov2 = __shfl_xor(bv2[b], m);
                if (ov1 < bv1[b] || (ov1 == bv1[b] && ok1 < bk1[b])) {
                    bv2[b] = fminf(bv1[b], ov2);
                    bv1[b] = ov1; bk1[b] = ok1;
                } else {
                    bv2[b] = fminf(bv2[b], ov1);
                }
            }
        }
        if (tx == 0) {
#pragma unroll
            for (int b = 0; b < 4; ++b) {
                IDXR[r0 + b] = bk1[b];
                FLAGR[r0 + b] = (bv2[b] - bv1[b] >= MARGINF) ? 0 : 1;
            }
        }
    }
    __syncthreads();
    if (t < 32) {
        int row = row0 + t;
        if (FLAGR[t])
            atomicOr((unsigned int*)ws + WS_MASK + (row >> 5), 1u << (row & 31));
        out[row] = (float)IDXR[t];
    }
    float lvq = 0.f, lrec = 0.f;
    {
        int d = t & 127, rq = t >> 7;
        int cd = SWC(d);
#pragma unroll
        for (int e = 0; e < 4; ++e) {
            int rr = (rq + 2 * e) * 4;
            float4 en = *(const float4*)&X[d * 32 + (rr ^ cd)];
            float q0 = emb[(size_t)IDXR[rr + 0] * 128 + d];
            float q1 = emb[(size_t)IDXR[rr + 1] * 128 + d];
            float q2 = emb[(size_t)IDXR[rr + 2] * 128 + d];
            float q3 = emb[(size_t)IDXR[rr + 3] * 128 + d];
            float4 qv; qv.x = q0; qv.y = q1; qv.z = q2; qv.w = q3;
            *(float4*)&X[(128 + d) * 32 + (rr ^ cd)] = qv;
            if (!FLAGR[rr + 0]) lvq += (en.x - q0) * (en.x - q0);
            if (!FLAGR[rr + 1]) lvq += (en.y - q1) * (en.y - q1);
            if (!FLAGR[rr + 2]) lvq += (en.z - q2) * (en.z - q2);
            if (!FLAGR[rr + 3]) lvq += (en.w - q3) * (en.w - q3);
            out[NB + (size_t)(row0 + rr + 0) * 128 + d] = q0;
            out[NB + (size_t)(row0 + rr + 1) * 128 + d] = q1;
            out[NB + (size_t)(row0 + rr + 2) * 128 + d] = q2;
            out[NB + (size_t)(row0 + rr + 3) * 128 + d] = q3;
        }
    }
    __syncthreads();
    gemm_out256(d1w, d1b, 128, X + 128 * 32, Y, WC, t, tx, r0, true);
    gemm_out256(d2w, d2b, 256, Y, X, WC, t, tx, r0, true);
    if (t < 192) {
        int jj = t >> 5, r = t & 31;
        const float* wr = rw + jj * 256;
        float a0 = 0.f, a1 = 0.f, a2 = 0.f, a3 = 0.f;
        for (int i = 0; i < 256; i += 4) {
            a0 += wr[i] * X[i * 32 + (r ^ SWC(i))];
            a1 += wr[i + 1] * X[(i + 1) * 32 + (r ^ SWC(i + 1))];
            a2 += wr[i + 2] * X[(i + 2) * 32 + (r ^ SWC(i + 2))];
            a3 += wr[i + 3] * X[(i + 3) * 32 + (r ^ SWC(i + 3))];
        }
        float rec = tanhf(rb[jj] + (a0 + a1) + (a2 + a3));
        float df = rec - AT[jj * 32 + r];
        if (!FLAGR[r]) lrec = df * df;
    }
#pragma unroll
    for (int m = 1; m < 64; m <<= 1) {
        lvq += __shfl_xor(lvq, m);
        lrec += __shfl_xor(lrec, m);
    }
    if ((t & 63) == 0) { RED[t >> 6] = lvq; RED[4 + (t >> 6)] = lrec; }
    __syncthreads();
    if (t == 0) {
        int slot = blockIdx.x & 63;
        atomicAdd((double*)ws + slot, (double)((RED[0] + RED[1]) + (RED[2] + RED[3])));
        atomicAdd((double*)ws + 64 + slot, (double)((RED[4] + RED[5]) + (RED[6] + RED[7])));
    }
}

extern "C" void kernel_launch(void* const* d_in, const int* in_sizes, int n_in,
                              void* d_out, int out_size, void* d_ws, size_t ws_size,
                              hipStream_t stream) {
    const float* action = (const float*)d_in[0];
    const float* w1 = (const float*)d_in[1];
    const float* b1 = (const float*)d_in[2];
    const float* w2 = (const float*)d_in[3];
    const float* b2 = (const float*)d_in[4];
    const float* w3 = (const float*)d_in[5];
    const float* b3 = (const float*)d_in[6];
    const float* emb = (const float*)d_in[7];
    const float* d1w = (const float*)d_in[8];
    const float* d1b = (const float*)d_in[9];
    const float* d2w = (const float*)d_in[10];
    const float* d2b = (const float*)d_in[11];
    const float* rw = (const float*)d_in[12];
    const float* rb = (const float*)d_in[13];
    float* out = (float*)d_out;
    float* ws = (float*)d_ws;

    const size_t need_mfma = (size_t)WS_BASE_BYTES + (size_t)SPLIT_TOTAL * 2;
    const int use_mfma = (ws_size >= need_mfma) ? 1 : 0;
    const int dyn_lds = 64 * 264 * 2 * 2;  // 67584 B

    prep_kernel<<<1043, 256, 0, stream>>>(w2, w3, emb, d1w, d2w, rw, ws, use_mfma);
    if (use_mfma) {
        hipFuncSetAttribute((const void*)vqvae_main_mfma,
                            hipFuncAttributeMaxDynamicSharedMemorySize, dyn_lds);
        vqvae_main_mfma<<<NB / 64, 256, dyn_lds, stream>>>(action, w1, b1, b2, b3, emb,
                                                           d1b, d2b, rb, out, ws);
    } else {
        vqvae_main_fp32<<<NB / 32, 256, 0, stream>>>(action, w1, b1, w2, b2, w3, b3, emb,
                                                     d1w, d1b, d2w, d2b, rw, rb, out, ws);
    }
    vqvae_fix<<<256, 256, 0, stream>>>(action, w1, b1, w2, b2, w3, b3, emb,
                                       d1w, d1b, d2w, d2b, rw, rb, out, ws);
    vqvae_fin<<<1, 64, 0, stream>>>(ws, out);
}

// Round 10
// 405.720 us; speedup vs baseline: 3.6089x; 3.6089x over previous
//
#include <hip/hip_runtime.h>
#include <hip/hip_bf16.h>

#define NB 131072
#define MARGINF 5e-7f
// ws layout: doubles[128] at float idx 0..255 (vq slots 0..63, rec slots 64..127);
// e2[512] at float idx 256..767; bitmask u32[4096] at word idx 768..4863;
// bf16 split-weight region from float idx 4864.
#define WS_E2 256
#define WS_MASK 768
#define WS_MASKW 4096
#define WS_BASE_BYTES ((768 + 4096) * 4)
#define WS_SPLIT_F 4864
// split region offsets (bf16 element units, relative to split base)
#define OFF_W2 0
#define OFF_W3 131072
#define OFF_EMB 196608
#define OFF_D1 327680
#define OFF_D2 393216
#define OFF_RW 524288
#define SPLIT_TOTAL 532480

typedef __attribute__((ext_vector_type(8))) short short8v;
typedef __attribute__((ext_vector_type(4))) float f32x4;
typedef __attribute__((ext_vector_type(4))) unsigned short ushort4v;

#define SWC(j) ((((j) >> 2) & 7) << 2)

__device__ __forceinline__ unsigned short bf16rn(float x) {
    unsigned u = __float_as_uint(x);
    unsigned r = u + 0x7fffu + ((u >> 16) & 1u);
    return (unsigned short)(r >> 16);
}
__device__ __forceinline__ void split2(float x, unsigned short& h, unsigned short& l) {
    h = bf16rn(x);
    float hf = __uint_as_float((unsigned)h << 16);
    l = bf16rn(x - hf);
}

// ---------------- prep: zero accum/mask + e2 + fragment-linear bf16 splits ----------------
__global__ void prep_kernel(
    const float* __restrict__ w2, const float* __restrict__ w3,
    const float* __restrict__ emb, const float* __restrict__ d1w,
    const float* __restrict__ d2w, const float* __restrict__ rw,
    float* __restrict__ ws, int do_splits)
{
    const int gid = blockIdx.x * 256 + threadIdx.x;
    const int stride = gridDim.x * 256;
    // zero loss slots (float idx 0..255) and flag mask (768..4863)
    for (int z = gid; z < 4352; z += stride) {
        int a = (z < 256) ? z : (512 + z);
        ws[a] = 0.f;
    }
    const int total = 512 + 266240;
    unsigned short* wsb = (unsigned short*)(ws + WS_SPLIT_F);
    for (int idx = gid; idx < total; idx += stride) {
        if (idx < 512) {
            const float* e = emb + (size_t)idx * 128;
            float s0 = 0.f, s1 = 0.f, s2 = 0.f, s3 = 0.f;
            for (int d = 0; d < 128; d += 4) {
                s0 += e[d] * e[d];     s1 += e[d + 1] * e[d + 1];
                s2 += e[d + 2] * e[d + 2]; s3 += e[d + 3] * e[d + 3];
            }
            ws[WS_E2 + idx] = (s0 + s1) + (s2 + s3);
            continue;
        }
        if (!do_splits) continue;
        int j = idx - 512;
        int base, K, o, k;
        float src;
        bool wlo;
        if (j < 65536) {            // w2: 256x256 (3-term consumer: lo needed)
            o = j >> 8; k = j & 255; base = OFF_W2; K = 256; src = w2[o * 256 + k]; wlo = true;
        } else if (j < 98304) {     // w3: 128x256 (3-term consumer)
            j -= 65536; o = j >> 8; k = j & 255; base = OFF_W3; K = 256; src = w3[o * 256 + k]; wlo = true;
        } else if (j < 163840) {    // emb: 512x128 (coarse hi-only consumer)
            j -= 98304; o = j >> 7; k = j & 127; base = OFF_EMB; K = 128; src = emb[o * 128 + k]; wlo = false;
        } else if (j < 196608) {    // d1w: 256x128 (hi-only)
            j -= 163840; o = j >> 7; k = j & 127; base = OFF_D1; K = 128; src = d1w[o * 128 + k]; wlo = false;
        } else if (j < 262144) {    // d2w: 256x256 (hi-only)
            j -= 196608; o = j >> 8; k = j & 255; base = OFF_D2; K = 256; src = d2w[o * 256 + k]; wlo = false;
        } else {                    // rw padded to 16 rows: 16x256 (hi-only)
            j -= 262144; o = j >> 8; k = j & 255; base = OFF_RW; K = 256;
            src = (o < 6) ? rw[o * 256 + k] : 0.f; wlo = false;
        }
        unsigned short h, l;
        split2(src, h, l);
        int jt = o >> 4, c = k >> 5;
        int lane = (((k >> 3) & 3) << 4) | (o & 15);
        int e = k & 7;
        int a = base + ((jt * (K >> 5) + c) * 2) * 512 + lane * 8 + e;
        wsb[a] = h;
        if (wlo) wsb[a + 512] = l;
    }
}

// ---------------- MFMA main kernel: 64 rows/block, 4 waves ----------------
// Activations hi/lo bf16 in dynamic LDS [64 rows][264]. Weight frags from ws (L2).
// TERMS=3: error-compensated. TERMS=1: hi-only. WRITELO: store lo split of outputs.

template<int NJT, int KC, bool RELU, bool SQSUM, int TERMS, bool WRITELO>
__device__ __forceinline__ void mfma_mlp4(
    const short8v* __restrict__ Wf, const float* __restrict__ bias,
    unsigned short* HHp, unsigned short* HLp, float* ENC2Wp,
    int w, int lane)
{
    const int lc = lane & 15, lg = lane >> 4;
    f32x4 acc[NJT][4];
#pragma unroll
    for (int jj = 0; jj < NJT; ++jj)
#pragma unroll
        for (int rt = 0; rt < 4; ++rt)
            acc[jj][rt] = (f32x4){0.f, 0.f, 0.f, 0.f};

    __syncthreads();  // inputs ready
    for (int c = 0; c < KC; ++c) {
        const int boff = c * 32 + lg * 8;
        short8v bh[4], bl[4];
#pragma unroll
        for (int rt = 0; rt < 4; ++rt) {
            bh[rt] = *(const short8v*)&HHp[(rt * 16 + lc) * 264 + boff];
            if (TERMS == 3)
                bl[rt] = *(const short8v*)&HLp[(rt * 16 + lc) * 264 + boff];
        }
#pragma unroll
        for (int jj = 0; jj < NJT; ++jj) {
            int fi = (((w * NJT + jj) * KC + c) * 2) * 64 + lane;
            short8v ah = Wf[fi];
            if (TERMS == 3) {
                short8v al = Wf[fi + 64];
#pragma unroll
                for (int rt = 0; rt < 4; ++rt) {
                    acc[jj][rt] = __builtin_amdgcn_mfma_f32_16x16x32_bf16(al, bh[rt], acc[jj][rt], 0, 0, 0);
                    acc[jj][rt] = __builtin_amdgcn_mfma_f32_16x16x32_bf16(ah, bl[rt], acc[jj][rt], 0, 0, 0);
                    acc[jj][rt] = __builtin_amdgcn_mfma_f32_16x16x32_bf16(ah, bh[rt], acc[jj][rt], 0, 0, 0);
                }
            } else {
#pragma unroll
                for (int rt = 0; rt < 4; ++rt)
                    acc[jj][rt] = __builtin_amdgcn_mfma_f32_16x16x32_bf16(ah, bh[rt], acc[jj][rt], 0, 0, 0);
            }
        }
    }
    __syncthreads();  // all reads done; in-place writes now safe

    float sq[4] = {0.f, 0.f, 0.f, 0.f};
#pragma unroll
    for (int jj = 0; jj < NJT; ++jj) {
        int j0 = (w * NJT + jj) * 16 + lg * 4;
        float4 bv = *(const float4*)&bias[j0];
        float bb[4] = {bv.x, bv.y, bv.z, bv.w};
#pragma unroll
        for (int rt = 0; rt < 4; ++rt) {
            int r = rt * 16 + lc;
            ushort4v hv, lv;
#pragma unroll
            for (int reg = 0; reg < 4; ++reg) {
                float v = acc[jj][rt][reg] + bb[reg];
                if (RELU) v = fmaxf(v, 0.f);
                if (SQSUM) sq[rt] += v * v;
                if (WRITELO) {
                    unsigned short h, l;
                    split2(v, h, l);
                    hv[reg] = h; lv[reg] = l;
                } else {
                    hv[reg] = bf16rn(v);
                }
            }
            *(ushort4v*)&HHp[r * 264 + j0] = hv;
            if (WRITELO) *(ushort4v*)&HLp[r * 264 + j0] = lv;
        }
    }
    if (SQSUM) {
#pragma unroll
        for (int rt = 0; rt < 4; ++rt) {
            float s = sq[rt];
            s += __shfl_xor(s, 16);
            s += __shfl_xor(s, 32);
            if (lg == 0) ENC2Wp[w * 64 + rt * 16 + lc] = s;
        }
    }
}

__global__ __launch_bounds__(256, 2) void vqvae_main_mfma(
    const float* __restrict__ action,
    const float* __restrict__ w1, const float* __restrict__ b1,
    const float* __restrict__ b2, const float* __restrict__ b3,
    const float* __restrict__ emb,
    const float* __restrict__ d1b, const float* __restrict__ d2b,
    const float* __restrict__ rb,
    float* __restrict__ out, float* __restrict__ ws)
{
    extern __shared__ __align__(16) unsigned short DYN[];
    unsigned short* HH = DYN;              // [64][264]
    unsigned short* HL = DYN + 64 * 264;   // [64][264]

    __shared__ float AT[64 * 6];
    __shared__ float E2S[512];
    __shared__ float ENC2W[4 * 64];
    __shared__ float ENC2F[64];
    __shared__ float WMIN[4][64];
    __shared__ float CMIN[64];             // coarse min + per-row window
    __shared__ unsigned int CAND[64 * 16];
    __shared__ int IDXR[64];
    __shared__ int FLAGR[64];
    __shared__ float RED[8];

    const int t = threadIdx.x;
    const int w = t >> 6, lane = t & 63;
    const int lc = lane & 15, lg = lane >> 4;
    const int row0 = blockIdx.x * 64;
    const unsigned short* wsb = (const unsigned short*)(ws + WS_SPLIT_F);
    const short8v* W2f = (const short8v*)wsb + OFF_W2 / 8;
    const short8v* W3f = (const short8v*)wsb + OFF_W3 / 8;
    const short8v* EMBf = (const short8v*)wsb + OFF_EMB / 8;
    const short8v* D1f = (const short8v*)wsb + OFF_D1 / 8;
    const short8v* D2f = (const short8v*)wsb + OFF_D2 / 8;
    const short8v* RWf = (const short8v*)wsb + OFF_RW / 8;

    // ---- stage action (row-major [r][6]) + e2 ----
    for (int i = t; i < 384; i += 256) AT[i] = action[(size_t)row0 * 6 + i];
    for (int i = t; i < 512; i += 256) E2S[i] = ws[WS_E2 + i];
    __syncthreads();

    // ---- enc1 (VALU fp32): h1[j=t][r=0..63] -> splits ----
    {
        float wr[6];
#pragma unroll
        for (int i = 0; i < 6; ++i) wr[i] = w1[t * 6 + i];
        float bb = b1[t];
        for (int r = 0; r < 64; ++r) {
            float s = bb;
#pragma unroll
            for (int i = 0; i < 6; ++i) s += wr[i] * AT[r * 6 + i];
            s = fmaxf(s, 0.f);
            unsigned short h, l;
            split2(s, h, l);
            HH[r * 264 + t] = h;
            HL[r * 264 + t] = l;
        }
    }

    // ---- enc2: 256 -> 256 relu (3-term) ----
    mfma_mlp4<4, 8, true, false, 3, true>(W2f, b2, HH, HL, ENC2W, w, lane);
    // ---- mu: 256 -> 128, no relu, + per-row ||enc||^2 (3-term, hi/lo out) ----
    mfma_mlp4<2, 8, false, true, 3, true>(W3f, b3, HH, HL, ENC2W, w, lane);

    // ---- VQ stage 1, sweep A: coarse row-min via hi-only MFMA (register-light) ----
    float lvq = 0.f, lrec = 0.f;
    {
        for (int i = t; i < 1024; i += 256) CAND[i] = 0u;
        float v1[4][4];
#pragma unroll
        for (int rt = 0; rt < 4; ++rt)
#pragma unroll
            for (int reg = 0; reg < 4; ++reg) v1[rt][reg] = 1e30f;
        __syncthreads();  // enc splits + CAND zero ready
        for (int p = 0; p < 2; ++p) {
            f32x4 vacc[4][4];
#pragma unroll
            for (int kt = 0; kt < 4; ++kt)
#pragma unroll
                for (int rt = 0; rt < 4; ++rt)
                    vacc[kt][rt] = (f32x4){0.f, 0.f, 0.f, 0.f};
            for (int c = 0; c < 4; ++c) {
                const int aoff = c * 32 + lg * 8;
                short8v ah[4];
#pragma unroll
                for (int rt = 0; rt < 4; ++rt)
                    ah[rt] = *(const short8v*)&HH[(rt * 16 + lc) * 264 + aoff];
#pragma unroll
                for (int kt = 0; kt < 4; ++kt) {
                    int ktg = w * 8 + p * 4 + kt;
                    short8v bh = EMBf[((ktg * 4 + c) * 2) * 64 + lane];
#pragma unroll
                    for (int rt = 0; rt < 4; ++rt)
                        vacc[kt][rt] = __builtin_amdgcn_mfma_f32_16x16x32_bf16(ah[rt], bh, vacc[kt][rt], 0, 0, 0);
                }
            }
            // fold into running min, then DISCARD vacc (no long-lived accumulators)
#pragma unroll
            for (int kt = 0; kt < 4; ++kt) {
                int k = (w * 8 + p * 4 + kt) * 16 + lc;
                float ek = E2S[k];
#pragma unroll
                for (int rt = 0; rt < 4; ++rt)
#pragma unroll
                    for (int reg = 0; reg < 4; ++reg)
                        v1[rt][reg] = fminf(v1[rt][reg], ek - 2.f * vacc[kt][rt][reg]);
            }
        }
        // lane-merge min across the 16 lc lanes
#pragma unroll
        for (int m = 1; m < 16; m <<= 1)
#pragma unroll
            for (int rt = 0; rt < 4; ++rt)
#pragma unroll
                for (int reg = 0; reg < 4; ++reg)
                    v1[rt][reg] = fminf(v1[rt][reg], __shfl_xor(v1[rt][reg], m));
        if (lc == 0) {
#pragma unroll
            for (int rt = 0; rt < 4; ++rt)
#pragma unroll
                for (int reg = 0; reg < 4; ++reg)
                    WMIN[w][rt * 16 + lg * 4 + reg] = v1[rt][reg];
        }
        __syncthreads();
        if (t < 64) {
            float cm = fminf(fminf(WMIN[0][t], WMIN[1][t]), fminf(WMIN[2][t], WMIN[3][t]));
            float e2r = ENC2W[0 * 64 + t] + ENC2W[1 * 64 + t] +
                        ENC2W[2 * 64 + t] + ENC2W[3 * 64 + t];
            ENC2F[t] = e2r;
            // rigorous window: 2*CauchySchwarz(coarse-vs-exact) + margin slack,
            // E <= 1.0e-4 * ||enc||  ->  window = 2.2e-4*sqrt(enc2) + 2e-6
            CMIN[t] = cm + 2.2e-4f * sqrtf(e2r) + 2e-6f;
        }
        __syncthreads();

        // ---- sweep B: recompute coarse dd, collect candidates within window ----
        for (int p = 0; p < 2; ++p) {
            f32x4 vacc[4][4];
#pragma unroll
            for (int kt = 0; kt < 4; ++kt)
#pragma unroll
                for (int rt = 0; rt < 4; ++rt)
                    vacc[kt][rt] = (f32x4){0.f, 0.f, 0.f, 0.f};
            for (int c = 0; c < 4; ++c) {
                const int aoff = c * 32 + lg * 8;
                short8v ah[4];
#pragma unroll
                for (int rt = 0; rt < 4; ++rt)
                    ah[rt] = *(const short8v*)&HH[(rt * 16 + lc) * 264 + aoff];
#pragma unroll
                for (int kt = 0; kt < 4; ++kt) {
                    int ktg = w * 8 + p * 4 + kt;
                    short8v bh = EMBf[((ktg * 4 + c) * 2) * 64 + lane];
#pragma unroll
                    for (int rt = 0; rt < 4; ++rt)
                        vacc[kt][rt] = __builtin_amdgcn_mfma_f32_16x16x32_bf16(ah[rt], bh, vacc[kt][rt], 0, 0, 0);
                }
            }
#pragma unroll
            for (int kt = 0; kt < 4; ++kt) {
                int k = (w * 8 + p * 4 + kt) * 16 + lc;
                float ek = E2S[k];
#pragma unroll
                for (int rt = 0; rt < 4; ++rt)
#pragma unroll
                    for (int reg = 0; reg < 4; ++reg) {
                        int row = rt * 16 + lg * 4 + reg;
                        float dd = ek - 2.f * vacc[kt][rt][reg];
                        if (!(dd > CMIN[row]))  // NaN-safe: NaN -> candidate
                            atomicOr(&CAND[row * 16 + (k >> 5)], 1u << (k & 31));
                    }
            }
        }
    }
    __syncthreads();

    // ---- VQ stage 2: wave-parallel exact fp32 rescore (4 lanes per row) ----
    {
        const int row = w * 16 + lc;   // wave w owns rows w*16 .. w*16+15
        float v1 = 1e30f, v2 = 1e30f; int k1 = 0;
#pragma unroll
        for (int wi = 0; wi < 4; ++wi) {
            int wd = lg * 4 + wi;      // 4 lanes split the 16 words
            unsigned int m = CAND[row * 16 + wd];
            while (m) {
                int b = __ffs(m) - 1; m &= m - 1;
                int k = wd * 32 + b;
                const float* ek = emb + (size_t)k * 128;
                float s0 = 0.f, s1 = 0.f;
#pragma unroll 8
                for (int d = 0; d < 128; d += 2) {
                    unsigned hh2 = *(const unsigned*)&HH[row * 264 + d];
                    unsigned hl2 = *(const unsigned*)&HL[row * 264 + d];
                    float e0 = __uint_as_float(hh2 << 16) + __uint_as_float(hl2 << 16);
                    float e1 = __uint_as_float(hh2 & 0xffff0000u) + __uint_as_float(hl2 & 0xffff0000u);
                    s0 += e0 * ek[d];
                    s1 += e1 * ek[d + 1];
                }
                float dd = E2S[k] - 2.f * (s0 + s1);
                if (dd < v1) { v2 = v1; v1 = dd; k1 = k; }
                else if (dd < v2) v2 = dd;
            }
        }
        // merge the 4 sub-lanes (xor 16, 32) with smaller-k tie-break
#pragma unroll
        for (int m2 = 16; m2 <= 32; m2 <<= 1) {
            float ov1 = __shfl_xor(v1, m2);
            int ok1 = __shfl_xor(k1, m2);
            float ov2 = __shfl_xor(v2, m2);
            if (ov1 < v1 || (ov1 == v1 && ok1 < k1)) {
                v2 = fminf(v1, ov2);
                v1 = ov1; k1 = ok1;
            } else {
                v2 = fminf(v2, ov1);
            }
        }
        if (lg == 0) {
            int flag = (v2 - v1 >= MARGINF) ? 0 : 1;  // NaN-safe
            IDXR[row] = k1;
            FLAGR[row] = flag;
            int grow = row0 + row;
            if (flag)
                atomicOr((unsigned int*)ws + WS_MASK + (grow >> 5), 1u << (grow & 31));
            out[grow] = (float)k1;
            if (!flag) lvq = ENC2F[row] + v1;
        }
    }
    __syncthreads();

    // ---- gather q (exact fp32), write q_st, hi-only split for decoder ----
    {
        int d = t & 127, rhalf = t >> 7;
#pragma unroll
        for (int e = 0; e < 32; ++e) {
            int r = (e << 1) | rhalf;
            int k1 = IDXR[r];
            float q = emb[(size_t)k1 * 128 + d];
            out[NB + (size_t)(row0 + r) * 128 + d] = q;
            HH[r * 264 + d] = bf16rn(q);
        }
    }

    // ---- decoder (hi-only, 1-term) ----
    mfma_mlp4<4, 4, true, false, 1, false>(D1f, d1b, HH, HL, ENC2W, w, lane);
    mfma_mlp4<4, 8, true, false, 1, false>(D2f, d2b, HH, HL, ENC2W, w, lane);
    __syncthreads();  // dec2 hi ready

    // ---- rec: wave w handles rows w*16..+15 via MFMA (hi-only) ----
    {
        f32x4 racc = (f32x4){0.f, 0.f, 0.f, 0.f};
        for (int c = 0; c < 8; ++c) {
            const int boff = c * 32 + lg * 8;
            short8v bh = *(const short8v*)&HH[(w * 16 + lc) * 264 + boff];
            int fi = (c * 2) * 64 + lane;
            short8v ah = RWf[fi];
            racc = __builtin_amdgcn_mfma_f32_16x16x32_bf16(ah, bh, racc, 0, 0, 0);
        }
        int r = w * 16 + lc;
#pragma unroll
        for (int reg = 0; reg < 4; ++reg) {
            int j = lg * 4 + reg;
            if (j < 6) {
                float rec = tanhf(racc[reg] + rb[j]);
                float df = rec - AT[r * 6 + j];
                if (!FLAGR[r]) lrec += df * df;
            }
        }
    }

    // ---- block loss reduction -> hashed fp64 slots ----
#pragma unroll
    for (int m = 1; m < 64; m <<= 1) {
        lvq += __shfl_xor(lvq, m);
        lrec += __shfl_xor(lrec, m);
    }
    if ((t & 63) == 0) { RED[t >> 6] = lvq; RED[4 + (t >> 6)] = lrec; }
    __syncthreads();
    if (t == 0) {
        int slot = blockIdx.x & 63;
        atomicAdd((double*)ws + slot, (double)((RED[0] + RED[1]) + (RED[2] + RED[3])));
        atomicAdd((double*)ws + 64 + slot, (double)((RED[4] + RED[5]) + (RED[6] + RED[7])));
    }
}

// ---------------- fp64 repair of ambiguous rows (256 blocks, stride over words) ----------------
__global__ __launch_bounds__(256) void vqvae_fix(
    const float* __restrict__ action,
    const float* __restrict__ w1, const float* __restrict__ b1,
    const float* __restrict__ w2, const float* __restrict__ b2,
    const float* __restrict__ w3, const float* __restrict__ b3,
    const float* __restrict__ emb,
    const float* __restrict__ d1w, const float* __restrict__ d1b,
    const float* __restrict__ d2w, const float* __restrict__ d2b,
    const float* __restrict__ rw, const float* __restrict__ rb,
    float* __restrict__ out, float* __restrict__ ws)
{
    __shared__ double H1[256];
    __shared__ double H2[256];
    __shared__ double ENC[128];
    __shared__ double QD[128];
    __shared__ double SRED[256];
    __shared__ int SK[256];
    __shared__ double SA[6];

    const int t = threadIdx.x;

    for (int widx = blockIdx.x; widx < WS_MASKW; widx += gridDim.x) {
        const unsigned int word = ((const unsigned int*)ws)[WS_MASK + widx];
        if (word == 0u) continue;  // uniform across block

        for (int bit = 0; bit < 32; ++bit) {
            if (!(word & (1u << bit))) continue;
            const int row = (widx << 5) + bit;

            if (t < 6) SA[t] = (double)action[(size_t)row * 6 + t];
            __syncthreads();
            {
                double a = (double)b1[t];
#pragma unroll
                for (int i = 0; i < 6; ++i) a += (double)w1[t * 6 + i] * SA[i];
                H1[t] = a > 0.0 ? a : 0.0;
            }
            __syncthreads();
            {
                const float* w = w2 + (size_t)t * 256;
                double a0 = 0, a1 = 0, a2 = 0, a3 = 0;
                for (int i = 0; i < 256; i += 4) {
                    a0 += (double)w[i] * H1[i];     a1 += (double)w[i + 1] * H1[i + 1];
                    a2 += (double)w[i + 2] * H1[i + 2]; a3 += (double)w[i + 3] * H1[i + 3];
                }
                double a = (double)b2[t] + a0 + a1 + a2 + a3;
                H2[t] = a > 0.0 ? a : 0.0;
            }
            __syncthreads();
            if (t < 128) {
                const float* w = w3 + (size_t)t * 256;
                double a0 = 0, a1 = 0, a2 = 0, a3 = 0;
                for (int i = 0; i < 256; i += 4) {
                    a0 += (double)w[i] * H2[i];     a1 += (double)w[i + 1] * H2[i + 1];
                    a2 += (double)w[i + 2] * H2[i + 2]; a3 += (double)w[i + 3] * H2[i + 3];
                }
                ENC[t] = (double)b3[t] + a0 + a1 + a2 + a3;
            }
            __syncthreads();
            double best = 1e300; int bk = 0;
#pragma unroll
            for (int kk = 0; kk < 2; ++kk) {
                int k = t + kk * 256;
                const float* e = emb + (size_t)k * 128;
                double s0 = 0, s1 = 0;
                for (int d = 0; d < 128; d += 2) {
                    double df0 = ENC[d] - (double)e[d];
                    double df1 = ENC[d + 1] - (double)e[d + 1];
                    s0 += df0 * df0; s1 += df1 * df1;
                }
                double s = s0 + s1;
                if (s < best) { best = s; bk = k; }
            }
            SRED[t] = best; SK[t] = bk;
            __syncthreads();
            for (int st = 128; st > 0; st >>= 1) {
                if (t < st) {
                    double ov = SRED[t + st]; int ok = SK[t + st];
                    if (ov < SRED[t] || (ov == SRED[t] && ok < SK[t])) { SRED[t] = ov; SK[t] = ok; }
                }
                __syncthreads();
            }
            const int bestk = SK[0];
            double lv = 0.0;
            if (t < 128) {
                double q = (double)emb[(size_t)bestk * 128 + t];
                QD[t] = q;
                double df = ENC[t] - q;
                lv = df * df;
                out[NB + (size_t)row * 128 + t] = (float)q;
            }
            if (t == 0) out[row] = (float)bestk;
            __syncthreads();
            {
                const float* w = d1w + (size_t)t * 128;
                double a0 = 0, a1 = 0;
                for (int i = 0; i < 128; i += 2) {
                    a0 += (double)w[i] * QD[i]; a1 += (double)w[i + 1] * QD[i + 1];
                }
                double a = (double)d1b[t] + a0 + a1;
                H1[t] = a > 0.0 ? a : 0.0;
            }
            __syncthreads();
            {
                const float* w = d2w + (size_t)t * 256;
                double a0 = 0, a1 = 0, a2 = 0, a3 = 0;
                for (int i = 0; i < 256; i += 4) {
                    a0 += (double)w[i] * H1[i];     a1 += (double)w[i + 1] * H1[i + 1];
                    a2 += (double)w[i + 2] * H1[i + 2]; a3 += (double)w[i + 3] * H1[i + 3];
                }
                double a = (double)d2b[t] + a0 + a1 + a2 + a3;
                H2[t] = a > 0.0 ? a : 0.0;
            }
            __syncthreads();
            double lr = 0.0;
            if (t < 6) {
                const float* w = rw + (size_t)t * 256;
                double a0 = 0, a1 = 0;
                for (int i = 0; i < 256; i += 2) {
                    a0 += (double)w[i] * H2[i]; a1 += (double)w[i + 1] * H2[i + 1];
                }
                double rec = tanh((double)rb[t] + a0 + a1);
                double df = rec - SA[t];
                lr = df * df;
            }
            SRED[t] = lv;
            __syncthreads();
            for (int st = 128; st > 0; st >>= 1) {
                if (t < st) SRED[t] += SRED[t + st];
                __syncthreads();
            }
            if (t == 0) atomicAdd((double*)ws + 0, SRED[0]);
            if (t < 6) atomicAdd((double*)ws + 64, lr);
            __syncthreads();
        }
    }
}

__global__ void vqvae_fin(const float* __restrict__ ws, float* __restrict__ out) {
    if (threadIdx.x == 0 && blockIdx.x == 0) {
        const double* D = (const double*)ws;
        double sv = 0.0, sr = 0.0;
        for (int i = 0; i < 64; ++i) { sv += D[i]; sr += D[64 + i]; }
        double loss = sr / ((double)NB * 6.0) + 1.25 * (sv / ((double)NB * 128.0));
        out[(size_t)NB * 129] = (float)loss;
    }
}

// ---------------- fp32 fallback (only if ws too small for splits) ----------------
static __device__ __forceinline__ void gemm_out256(
    const float* __restrict__ W, const float* __restrict__ bias, int IN,
    const float* __restrict__ hin, float* __restrict__ hout,
    float* __restrict__ WC, int t, int tx, int r0, bool do_relu)
{
    float acc[2][4][4];
#pragma unroll
    for (int g = 0; g < 2; ++g)
#pragma unroll
        for (int a = 0; a < 4; ++a)
#pragma unroll
            for (int b = 0; b < 4; ++b) acc[g][a][b] = 0.f;
    float4 pa = *(const float4*)(W + (size_t)t * IN);
    float4 pb = *(const float4*)(W + (size_t)t * IN + 4);
    for (int i0 = 0; i0 < IN; i0 += 8) {
        __syncthreads();
        WC[0 * 256 + t] = pa.x; WC[1 * 256 + t] = pa.y;
        WC[2 * 256 + t] = pa.z; WC[3 * 256 + t] = pa.w;
        WC[4 * 256 + t] = pb.x; WC[5 * 256 + t] = pb.y;
        WC[6 * 256 + t] = pb.z; WC[7 * 256 + t] = pb.w;
        __syncthreads();
        if (i0 + 8 < IN) {
            pa = *(const float4*)(W + (size_t)t * IN + i0 + 8);
            pb = *(const float4*)(W + (size_t)t * IN + i0 + 12);
        }
#pragma unroll
        for (int i = 0; i < 8; ++i) {
            int row = i0 + i;
            float4 h = *(const float4*)&hin[row * 32 + (r0 ^ SWC(row))];
            float4 w0 = *(const float4*)&WC[i * 256 + 4 * tx];
            float4 w1v = *(const float4*)&WC[i * 256 + 128 + 4 * tx];
            float wv0[4] = {w0.x, w0.y, w0.z, w0.w};
            float wv1[4] = {w1v.x, w1v.y, w1v.z, w1v.w};
            float hv[4] = {h.x, h.y, h.z, h.w};
#pragma unroll
            for (int a = 0; a < 4; ++a)
#pragma unroll
                for (int b = 0; b < 4; ++b) {
                    acc[0][a][b] += wv0[a] * hv[b];
                    acc[1][a][b] += wv1[a] * hv[b];
                }
        }
    }
#pragma unroll
    for (int g = 0; g < 2; ++g)
#pragma unroll
        for (int a = 0; a < 4; ++a) {
            int j = g * 128 + 4 * tx + a;
            float bj = bias[j];
            float4 v;
            v.x = acc[g][a][0] + bj; v.y = acc[g][a][1] + bj;
            v.z = acc[g][a][2] + bj; v.w = acc[g][a][3] + bj;
            if (do_relu) {
                v.x = fmaxf(v.x, 0.f); v.y = fmaxf(v.y, 0.f);
                v.z = fmaxf(v.z, 0.f); v.w = fmaxf(v.w, 0.f);
            }
            *(float4*)&hout[j * 32 + (r0 ^ SWC(j))] = v;
        }
    __syncthreads();
}

__global__ __launch_bounds__(256, 2) void vqvae_main_fp32(
    const float* __restrict__ action,
    const float* __restrict__ w1, const float* __restrict__ b1,
    const float* __restrict__ w2, const float* __restrict__ b2,
    const float* __restrict__ w3, const float* __restrict__ b3,
    const float* __restrict__ emb,
    const float* __restrict__ d1w, const float* __restrict__ d1b,
    const float* __restrict__ d2w, const float* __restrict__ d2b,
    const float* __restrict__ rw, const float* __restrict__ rb,
    float* __restrict__ out, float* __restrict__ ws)
{
    __shared__ float X[256 * 32];
    __shared__ float Y[256 * 32];
    __shared__ float WC[2048];
    __shared__ float AT[6 * 32];
    __shared__ int IDXR[32];
    __shared__ int FLAGR[32];
    __shared__ float RED[8];

    const int t = threadIdx.x;
    const int tx = t & 31, ty = t >> 5;
    const int r0 = ty * 4;
    const int row0 = blockIdx.x * 32;

    if (t < 192) {
        int r = t / 6, i = t - r * 6;
        AT[i * 32 + r] = action[(size_t)row0 * 6 + t];
    }
    __syncthreads();
    {
#pragma unroll
        for (int i = 0; i < 6; ++i) WC[i * 256 + t] = w1[t * 6 + i];
        __syncthreads();
        float acc[2][4][4];
#pragma unroll
        for (int g = 0; g < 2; ++g)
#pragma unroll
            for (int a = 0; a < 4; ++a)
#pragma unroll
                for (int b = 0; b < 4; ++b) acc[g][a][b] = 0.f;
#pragma unroll
        for (int i = 0; i < 6; ++i) {
            float4 h = *(const float4*)&AT[i * 32 + r0];
            float4 w0 = *(const float4*)&WC[i * 256 + 4 * tx];
            float4 w1v = *(const float4*)&WC[i * 256 + 128 + 4 * tx];
            float wv0[4] = {w0.x, w0.y, w0.z, w0.w};
            float wv1[4] = {w1v.x, w1v.y, w1v.z, w1v.w};
            float hv[4] = {h.x, h.y, h.z, h.w};
#pragma unroll
            for (int a = 0; a < 4; ++a)
#pragma unroll
                for (int b = 0; b < 4; ++b) {
                    acc[0][a][b] += wv0[a] * hv[b];
                    acc[1][a][b] += wv1[a] * hv[b];
                }
        }
#pragma unroll
        for (int g = 0; g < 2; ++g)
#pragma unroll
            for (int a = 0; a < 4; ++a) {
                int j = g * 128 + 4 * tx + a;
                float bj = b1[j];
                float4 v;
                v.x = fmaxf(acc[g][a][0] + bj, 0.f);
                v.y = fmaxf(acc[g][a][1] + bj, 0.f);
                v.z = fmaxf(acc[g][a][2] + bj, 0.f);
                v.w = fmaxf(acc[g][a][3] + bj, 0.f);
                *(float4*)&X[j * 32 + (r0 ^ SWC(j))] = v;
            }
        __syncthreads();
    }
    gemm_out256(w2, b2, 256, X, Y, WC, t, tx, r0, true);
    {
        float acc[4][4];
#pragma unroll
        for (int a = 0; a < 4; ++a)
#pragma unroll
            for (int b = 0; b < 4; ++b) acc[a][b] = 0.f;
        float4 pa, pb;
        if (t < 128) {
            pa = *(const float4*)(w3 + (size_t)t * 256);
            pb = *(const float4*)(w3 + (size_t)t * 256 + 4);
        }
        for (int i0 = 0; i0 < 256; i0 += 8) {
            __syncthreads();
            if (t < 128) {
                WC[0 * 128 + t] = pa.x; WC[1 * 128 + t] = pa.y;
                WC[2 * 128 + t] = pa.z; WC[3 * 128 + t] = pa.w;
                WC[4 * 128 + t] = pb.x; WC[5 * 128 + t] = pb.y;
                WC[6 * 128 + t] = pb.z; WC[7 * 128 + t] = pb.w;
            }
            __syncthreads();
            if (t < 128 && i0 + 8 < 256) {
                pa = *(const float4*)(w3 + (size_t)t * 256 + i0 + 8);
                pb = *(const float4*)(w3 + (size_t)t * 256 + i0 + 12);
            }
#pragma unroll
            for (int i = 0; i < 8; ++i) {
                int row = i0 + i;
                float4 h = *(const float4*)&Y[row * 32 + (r0 ^ SWC(row))];
                float4 w0 = *(const float4*)&WC[i * 128 + 4 * tx];
                float wv[4] = {w0.x, w0.y, w0.z, w0.w};
                float hv[4] = {h.x, h.y, h.z, h.w};
#pragma unroll
                for (int a = 0; a < 4; ++a)
#pragma unroll
                    for (int b = 0; b < 4; ++b) acc[a][b] += wv[a] * hv[b];
            }
        }
#pragma unroll
        for (int a = 0; a < 4; ++a) {
            int j = 4 * tx + a;
            float bj = b3[j];
            float4 v;
            v.x = acc[a][0] + bj; v.y = acc[a][1] + bj;
            v.z = acc[a][2] + bj; v.w = acc[a][3] + bj;
            *(float4*)&X[j * 32 + (r0 ^ SWC(j))] = v;
        }
        __syncthreads();
    }
    {
        float bv1[4], bv2[4];
        int bk1[4];
        float acc[4][4][4];
#pragma unroll
        for (int p = 0; p < 4; ++p)
#pragma unroll
            for (int a = 0; a < 4; ++a)
#pragma unroll
                for (int b = 0; b < 4; ++b) acc[p][a][b] = 0.f;
        float4 qa = *(const float4*)(emb + (size_t)t * 128);
        float4 qb = *(const float4*)(emb + (size_t)(t + 256) * 128);
        for (int d0 = 0; d0 < 128; d0 += 4) {
            __syncthreads();
            WC[0 * 512 + t] = qa.x; WC[1 * 512 + t] = qa.y;
            WC[2 * 512 + t] = qa.z; WC[3 * 512 + t] = qa.w;
            WC[0 * 512 + 256 + t] = qb.x; WC[1 * 512 + 256 + t] = qb.y;
            WC[2 * 512 + 256 + t] = qb.z; WC[3 * 512 + 256 + t] = qb.w;
            __syncthreads();
            if (d0 + 4 < 128) {
                qa = *(const float4*)(emb + (size_t)t * 128 + d0 + 4);
                qb = *(const float4*)(emb + (size_t)(t + 256) * 128 + d0 + 4);
            }
#pragma unroll
            for (int i = 0; i < 4; ++i) {
                int row = d0 + i;
                float4 h = *(const float4*)&X[row * 32 + (r0 ^ SWC(row))];
                float hv[4] = {h.x, h.y, h.z, h.w};
#pragma unroll
                for (int p = 0; p < 4; ++p) {
                    float4 w0 = *(const float4*)&WC[i * 512 + p * 128 + 4 * tx];
                    float wv[4] = {w0.x, w0.y, w0.z, w0.w};
#pragma unroll
                    for (int a = 0; a < 4; ++a)
#pragma unroll
                        for (int b = 0; b < 4; ++b) acc[p][a][b] += wv[a] * hv[b];
                }
            }
        }
#pragma unroll
        for (int b = 0; b < 4; ++b) { bv1[b] = 1e30f; bv2[b] = 1e30f; bk1[b] = 0; }
#pragma unroll
        for (int p = 0; p < 4; ++p)
#pragma unroll
            for (int a = 0; a < 4; ++a) {
                int k = p * 128 + 4 * tx + a;
                float ek = ws[WS_E2 + k];
#pragma unroll
                for (int b = 0; b < 4; ++b) {
                    float dd = ek - 2.f * acc[p][a][b];
                    if (dd < bv1[b]) { bv2[b] = bv1[b]; bv1[b] = dd; bk1[b] = k; }
                    else if (dd < bv2[b]) bv2[b] = dd;
                }
            }
#pragma unroll
        for (int m = 1; m < 32; m <<= 1) {
#pragma unroll
            for (int b = 0; b < 4; ++b) {
                float ov1 = __shfl_xor(bv1[b], m);
                int ok1 = __shfl_xor(bk1[b], m);
                float ov2 = __shfl_xor(bv2[b], m);
                if (ov1 < bv1[b] || (ov1 == bv1[b] && ok1 < bk1[b])) {
                    bv2[b] = fminf(bv1[b], ov2);
                    bv1[b] = ov1; bk1[b] = ok1;
                } else {
                    bv2[b] = fminf(bv2[b], ov1);
                }
            }
        }
        if (tx == 0) {
#pragma unroll
            for (int b = 0; b < 4; ++b) {
                IDXR[r0 + b] = bk1[b];
                FLAGR[r0 + b] = (bv2[b] - bv1[b] >= MARGINF) ? 0 : 1;
            }
        }
    }
    __syncthreads();
    if (t < 32) {
        int row = row0 + t;
        if (FLAGR[t])
            atomicOr((unsigned int*)ws + WS_MASK + (row >> 5), 1u << (row & 31));
        out[row] = (float)IDXR[t];
    }
    float lvq = 0.f, lrec = 0.f;
    {
        int d = t & 127, rq = t >> 7;
        int cd = SWC(d);
#pragma unroll
        for (int e = 0; e < 4; ++e) {
            int rr = (rq + 2 * e) * 4;
            float4 en = *(const float4*)&X[d * 32 + (rr ^ cd)];
            float q0 = emb[(size_t)IDXR[rr + 0] * 128 + d];
            float q1 = emb[(size_t)IDXR[rr + 1] * 128 + d];
            float q2 = emb[(size_t)IDXR[rr + 2] * 128 + d];
            float q3 = emb[(size_t)IDXR[rr + 3] * 128 + d];
            float4 qv; qv.x = q0; qv.y = q1; qv.z = q2; qv.w = q3;
            *(float4*)&X[(128 + d) * 32 + (rr ^ cd)] = qv;
            if (!FLAGR[rr + 0]) lvq += (en.x - q0) * (en.x - q0);
            if (!FLAGR[rr + 1]) lvq += (en.y - q1) * (en.y - q1);
            if (!FLAGR[rr + 2]) lvq += (en.z - q2) * (en.z - q2);
            if (!FLAGR[rr + 3]) lvq += (en.w - q3) * (en.w - q3);
            out[NB + (size_t)(row0 + rr + 0) * 128 + d] = q0;
            out[NB + (size_t)(row0 + rr + 1) * 128 + d] = q1;
            out[NB + (size_t)(row0 + rr + 2) * 128 + d] = q2;
            out[NB + (size_t)(row0 + rr + 3) * 128 + d] = q3;
        }
    }
    __syncthreads();
    gemm_out256(d1w, d1b, 128, X + 128 * 32, Y, WC, t, tx, r0, true);
    gemm_out256(d2w, d2b, 256, Y, X, WC, t, tx, r0, true);
    if (t < 192) {
        int jj = t >> 5, r = t & 31;
        const float* wr = rw + jj * 256;
        float a0 = 0.f, a1 = 0.f, a2 = 0.f, a3 = 0.f;
        for (int i = 0; i < 256; i += 4) {
            a0 += wr[i] * X[i * 32 + (r ^ SWC(i))];
            a1 += wr[i + 1] * X[(i + 1) * 32 + (r ^ SWC(i + 1))];
            a2 += wr[i + 2] * X[(i + 2) * 32 + (r ^ SWC(i + 2))];
            a3 += wr[i + 3] * X[(i + 3) * 32 + (r ^ SWC(i + 3))];
        }
        float rec = tanhf(rb[jj] + (a0 + a1) + (a2 + a3));
        float df = rec - AT[jj * 32 + r];
        if (!FLAGR[r]) lrec = df * df;
    }
#pragma unroll
    for (int m = 1; m < 64; m <<= 1) {
        lvq += __shfl_xor(lvq, m);
        lrec += __shfl_xor(lrec, m);
    }
    if ((t & 63) == 0) { RED[t >> 6] = lvq; RED[4 + (t >> 6)] = lrec; }
    __syncthreads();
    if (t == 0) {
        int slot = blockIdx.x & 63;
        atomicAdd((double*)ws + slot, (double)((RED[0] + RED[1]) + (RED[2] + RED[3])));
        atomicAdd((double*)ws + 64 + slot, (double)((RED[4] + RED[5]) + (RED[6] + RED[7])));
    }
}

extern "C" void kernel_launch(void* const* d_in, const int* in_sizes, int n_in,
                              void* d_out, int out_size, void* d_ws, size_t ws_size,
                              hipStream_t stream) {
    const float* action = (const float*)d_in[0];
    const float* w1 = (const float*)d_in[1];
    const float* b1 = (const float*)d_in[2];
    const float* w2 = (const float*)d_in[3];
    const float* b2 = (const float*)d_in[4];
    const float* w3 = (const float*)d_in[5];
    const float* b3 = (const float*)d_in[6];
    const float* emb = (const float*)d_in[7];
    const float* d1w = (const float*)d_in[8];
    const float* d1b = (const float*)d_in[9];
    const float* d2w = (const float*)d_in[10];
    const float* d2b = (const float*)d_in[11];
    const float* rw = (const float*)d_in[12];
    const float* rb = (const float*)d_in[13];
    float* out = (float*)d_out;
    float* ws = (float*)d_ws;

    const size_t need_mfma = (size_t)WS_BASE_BYTES + (size_t)SPLIT_TOTAL * 2;
    const int use_mfma = (ws_size >= need_mfma) ? 1 : 0;
    const int dyn_lds = 64 * 264 * 2 * 2;  // 67584 B

    prep_kernel<<<1043, 256, 0, stream>>>(w2, w3, emb, d1w, d2w, rw, ws, use_mfma);
    if (use_mfma) {
        hipFuncSetAttribute((const void*)vqvae_main_mfma,
                            hipFuncAttributeMaxDynamicSharedMemorySize, dyn_lds);
        vqvae_main_mfma<<<NB / 64, 256, dyn_lds, stream>>>(action, w1, b1, b2, b3, emb,
                                                           d1b, d2b, rb, out, ws);
    } else {
        vqvae_main_fp32<<<NB / 32, 256, 0, stream>>>(action, w1, b1, w2, b2, w3, b3, emb,
                                                     d1w, d1b, d2w, d2b, rw, rb, out, ws);
    }
    vqvae_fix<<<256, 256, 0, stream>>>(action, w1, b1, w2, b2, w3, b3, emb,
                                       d1w, d1b, d2w, d2b, rw, rb, out, ws);
    vqvae_fin<<<1, 64, 0, stream>>>(ws, out);
}

// Round 11
// 401.168 us; speedup vs baseline: 3.6499x; 1.0113x over previous
//
#include <hip/hip_runtime.h>
#include <hip/hip_bf16.h>

#define NB 131072
#define MARGINF 5e-7f
// ws layout: doubles[128] at float idx 0..255 (vq slots 0..63, rec slots 64..127);
// e2[512] at float idx 256..767; bitmask u32[4096] at word idx 768..4863;
// bf16 split-weight region from float idx 4864.
#define WS_E2 256
#define WS_MASK 768
#define WS_MASKW 4096
#define WS_BASE_BYTES ((768 + 4096) * 4)
#define WS_SPLIT_F 4864
// split region offsets (bf16 element units, relative to split base)
#define OFF_W2 0
#define OFF_W3 131072
#define OFF_EMB 196608
#define OFF_D1 327680
#define OFF_D2 393216
#define OFF_RW 524288
#define OFF_W1 532480
#define SPLIT_TOTAL 548864

typedef __attribute__((ext_vector_type(8))) short short8v;
typedef __attribute__((ext_vector_type(4))) float f32x4;
typedef __attribute__((ext_vector_type(4))) unsigned short ushort4v;

#define SWC(j) ((((j) >> 2) & 7) << 2)

__device__ __forceinline__ unsigned short bf16rn(float x) {
    unsigned u = __float_as_uint(x);
    unsigned r = u + 0x7fffu + ((u >> 16) & 1u);
    return (unsigned short)(r >> 16);
}
__device__ __forceinline__ void split2(float x, unsigned short& h, unsigned short& l) {
    h = bf16rn(x);
    float hf = __uint_as_float((unsigned)h << 16);
    l = bf16rn(x - hf);
}

// ---------------- prep: zero accum/mask + e2 + fragment-linear bf16 splits ----------------
__global__ void prep_kernel(
    const float* __restrict__ w1,
    const float* __restrict__ w2, const float* __restrict__ w3,
    const float* __restrict__ emb, const float* __restrict__ d1w,
    const float* __restrict__ d2w, const float* __restrict__ rw,
    float* __restrict__ ws, int do_splits)
{
    const int gid = blockIdx.x * 256 + threadIdx.x;
    const int stride = gridDim.x * 256;
    // zero loss slots (float idx 0..255) and flag mask (768..4863)
    for (int z = gid; z < 4352; z += stride) {
        int a = (z < 256) ? z : (512 + z);
        ws[a] = 0.f;
    }
    const int total = 512 + 274432;
    unsigned short* wsb = (unsigned short*)(ws + WS_SPLIT_F);
    for (int idx = gid; idx < total; idx += stride) {
        if (idx < 512) {
            const float* e = emb + (size_t)idx * 128;
            float s0 = 0.f, s1 = 0.f, s2 = 0.f, s3 = 0.f;
            for (int d = 0; d < 128; d += 4) {
                s0 += e[d] * e[d];     s1 += e[d + 1] * e[d + 1];
                s2 += e[d + 2] * e[d + 2]; s3 += e[d + 3] * e[d + 3];
            }
            ws[WS_E2 + idx] = (s0 + s1) + (s2 + s3);
            continue;
        }
        if (!do_splits) continue;
        int j = idx - 512;
        int base, K, o, k;
        float src;
        bool wlo;
        if (j < 65536) {            // w2: 256x256 (3-term consumer: lo needed)
            o = j >> 8; k = j & 255; base = OFF_W2; K = 256; src = w2[o * 256 + k]; wlo = true;
        } else if (j < 98304) {     // w3: 128x256 (3-term consumer)
            j -= 65536; o = j >> 8; k = j & 255; base = OFF_W3; K = 256; src = w3[o * 256 + k]; wlo = true;
        } else if (j < 163840) {    // emb: 512x128 (coarse hi-only consumer)
            j -= 98304; o = j >> 7; k = j & 127; base = OFF_EMB; K = 128; src = emb[o * 128 + k]; wlo = false;
        } else if (j < 196608) {    // d1w: 256x128 (hi-only)
            j -= 163840; o = j >> 7; k = j & 127; base = OFF_D1; K = 128; src = d1w[o * 128 + k]; wlo = false;
        } else if (j < 262144) {    // d2w: 256x256 (hi-only)
            j -= 196608; o = j >> 8; k = j & 255; base = OFF_D2; K = 256; src = d2w[o * 256 + k]; wlo = false;
        } else if (j < 266240) {    // rw padded to 16 rows: 16x256 (hi-only)
            j -= 262144; o = j >> 8; k = j & 255; base = OFF_RW; K = 256;
            src = (o < 6) ? rw[o * 256 + k] : 0.f; wlo = false;
        } else {                    // w1 padded K 6->32: 256x32 (3-term consumer)
            j -= 266240; o = j >> 5; k = j & 31; base = OFF_W1; K = 32;
            src = (k < 6) ? w1[o * 6 + k] : 0.f; wlo = true;
        }
        unsigned short h, l;
        split2(src, h, l);
        int jt = o >> 4, c = k >> 5;
        int lane = (((k >> 3) & 3) << 4) | (o & 15);
        int e = k & 7;
        int a = base + ((jt * (K >> 5) + c) * 2) * 512 + lane * 8 + e;
        wsb[a] = h;
        if (wlo) wsb[a + 512] = l;
    }
}

// ---------------- MFMA main kernel: 64 rows/block, 4 waves ----------------
// Activations hi/lo bf16 in dynamic LDS [64 rows][264]. Weight frags from ws (L2).
// TERMS=3: error-compensated. TERMS=1: hi-only. WRITELO: store lo split of outputs.

template<int NJT, int KC, bool RELU, bool SQSUM, int TERMS, bool WRITELO>
__device__ __forceinline__ void mfma_mlp4(
    const short8v* __restrict__ Wf, const float* __restrict__ bias,
    unsigned short* HHp, unsigned short* HLp, float* ENC2Wp,
    int w, int lane)
{
    const int lc = lane & 15, lg = lane >> 4;
    f32x4 acc[NJT][4];
#pragma unroll
    for (int jj = 0; jj < NJT; ++jj)
#pragma unroll
        for (int rt = 0; rt < 4; ++rt)
            acc[jj][rt] = (f32x4){0.f, 0.f, 0.f, 0.f};

    __syncthreads();  // inputs ready
    for (int c = 0; c < KC; ++c) {
        const int boff = c * 32 + lg * 8;
        short8v bh[4], bl[4];
#pragma unroll
        for (int rt = 0; rt < 4; ++rt) {
            bh[rt] = *(const short8v*)&HHp[(rt * 16 + lc) * 264 + boff];
            if (TERMS == 3)
                bl[rt] = *(const short8v*)&HLp[(rt * 16 + lc) * 264 + boff];
        }
#pragma unroll
        for (int jj = 0; jj < NJT; ++jj) {
            int fi = (((w * NJT + jj) * KC + c) * 2) * 64 + lane;
            short8v ah = Wf[fi];
            if (TERMS == 3) {
                short8v al = Wf[fi + 64];
#pragma unroll
                for (int rt = 0; rt < 4; ++rt) {
                    acc[jj][rt] = __builtin_amdgcn_mfma_f32_16x16x32_bf16(al, bh[rt], acc[jj][rt], 0, 0, 0);
                    acc[jj][rt] = __builtin_amdgcn_mfma_f32_16x16x32_bf16(ah, bl[rt], acc[jj][rt], 0, 0, 0);
                    acc[jj][rt] = __builtin_amdgcn_mfma_f32_16x16x32_bf16(ah, bh[rt], acc[jj][rt], 0, 0, 0);
                }
            } else {
#pragma unroll
                for (int rt = 0; rt < 4; ++rt)
                    acc[jj][rt] = __builtin_amdgcn_mfma_f32_16x16x32_bf16(ah, bh[rt], acc[jj][rt], 0, 0, 0);
            }
        }
    }
    __syncthreads();  // all reads done; in-place writes now safe

    float sq[4] = {0.f, 0.f, 0.f, 0.f};
#pragma unroll
    for (int jj = 0; jj < NJT; ++jj) {
        int j0 = (w * NJT + jj) * 16 + lg * 4;
        float4 bv = *(const float4*)&bias[j0];
        float bb[4] = {bv.x, bv.y, bv.z, bv.w};
#pragma unroll
        for (int rt = 0; rt < 4; ++rt) {
            int r = rt * 16 + lc;
            ushort4v hv, lv;
#pragma unroll
            for (int reg = 0; reg < 4; ++reg) {
                float v = acc[jj][rt][reg] + bb[reg];
                if (RELU) v = fmaxf(v, 0.f);
                if (SQSUM) sq[rt] += v * v;
                if (WRITELO) {
                    unsigned short h, l;
                    split2(v, h, l);
                    hv[reg] = h; lv[reg] = l;
                } else {
                    hv[reg] = bf16rn(v);
                }
            }
            *(ushort4v*)&HHp[r * 264 + j0] = hv;
            if (WRITELO) *(ushort4v*)&HLp[r * 264 + j0] = lv;
        }
    }
    if (SQSUM) {
#pragma unroll
        for (int rt = 0; rt < 4; ++rt) {
            float s = sq[rt];
            s += __shfl_xor(s, 16);
            s += __shfl_xor(s, 32);
            if (lg == 0) ENC2Wp[w * 64 + rt * 16 + lc] = s;
        }
    }
}

__global__ __launch_bounds__(256, 2) void vqvae_main_mfma(
    const float* __restrict__ action,
    const float* __restrict__ b1,
    const float* __restrict__ b2, const float* __restrict__ b3,
    const float* __restrict__ emb,
    const float* __restrict__ d1b, const float* __restrict__ d2b,
    const float* __restrict__ rb,
    float* __restrict__ out, float* __restrict__ ws)
{
    extern __shared__ __align__(16) unsigned short DYN[];
    unsigned short* HH = DYN;              // [64][264]
    unsigned short* HL = DYN + 64 * 264;   // [64][264]

    __shared__ float AT[64 * 6];
    __shared__ float E2S[512];
    __shared__ float ENC2W[4 * 64];
    __shared__ float ENC2F[64];
    __shared__ float WMIN[4][64];
    __shared__ float CMIN[64];             // coarse min + per-row window
    __shared__ unsigned int CAND[64 * 16];
    __shared__ int IDXR[64];
    __shared__ int FLAGR[64];
    __shared__ float RED[8];

    const int t = threadIdx.x;
    const int w = t >> 6, lane = t & 63;
    const int lc = lane & 15, lg = lane >> 4;
    const int row0 = blockIdx.x * 64;
    const unsigned short* wsb = (const unsigned short*)(ws + WS_SPLIT_F);
    const short8v* W1f = (const short8v*)wsb + OFF_W1 / 8;
    const short8v* W2f = (const short8v*)wsb + OFF_W2 / 8;
    const short8v* W3f = (const short8v*)wsb + OFF_W3 / 8;
    const short8v* EMBf = (const short8v*)wsb + OFF_EMB / 8;
    const short8v* D1f = (const short8v*)wsb + OFF_D1 / 8;
    const short8v* D2f = (const short8v*)wsb + OFF_D2 / 8;
    const short8v* RWf = (const short8v*)wsb + OFF_RW / 8;

    // ---- stage action (row-major [r][6]) + e2 ----
    for (int i = t; i < 384; i += 256) AT[i] = action[(size_t)row0 * 6 + i];
    for (int i = t; i < 512; i += 256) E2S[i] = ws[WS_E2 + i];
    __syncthreads();

    // ---- stage action as split B-operand (k<6 real, 6..31 zero) into HH/HL ----
    for (int i = t; i < 2048; i += 256) {
        int r = i >> 5, k = i & 31;
        float v = (k < 6) ? AT[r * 6 + k] : 0.f;
        unsigned short h, l;
        split2(v, h, l);
        HH[r * 264 + k] = h;
        HL[r * 264 + k] = l;
    }

    // ---- enc1 via MFMA: 6(pad32) -> 256 relu (3-term) ----
    mfma_mlp4<4, 1, true, false, 3, true>(W1f, b1, HH, HL, ENC2W, w, lane);
    // ---- enc2: 256 -> 256 relu (3-term) ----
    mfma_mlp4<4, 8, true, false, 3, true>(W2f, b2, HH, HL, ENC2W, w, lane);
    // ---- mu: 256 -> 128, no relu, + per-row ||enc||^2 (3-term, hi/lo out) ----
    mfma_mlp4<2, 8, false, true, 3, true>(W3f, b3, HH, HL, ENC2W, w, lane);

    // ---- VQ stage 1, sweep A: coarse row-min via hi-only MFMA (register-light) ----
    float lvq = 0.f, lrec = 0.f;
    {
        for (int i = t; i < 1024; i += 256) CAND[i] = 0u;
        float v1[4][4];
#pragma unroll
        for (int rt = 0; rt < 4; ++rt)
#pragma unroll
            for (int reg = 0; reg < 4; ++reg) v1[rt][reg] = 1e30f;
        __syncthreads();  // enc splits + CAND zero ready
        for (int p = 0; p < 2; ++p) {
            f32x4 vacc[4][4];
#pragma unroll
            for (int kt = 0; kt < 4; ++kt)
#pragma unroll
                for (int rt = 0; rt < 4; ++rt)
                    vacc[kt][rt] = (f32x4){0.f, 0.f, 0.f, 0.f};
            for (int c = 0; c < 4; ++c) {
                const int aoff = c * 32 + lg * 8;
                short8v ah[4];
#pragma unroll
                for (int rt = 0; rt < 4; ++rt)
                    ah[rt] = *(const short8v*)&HH[(rt * 16 + lc) * 264 + aoff];
#pragma unroll
                for (int kt = 0; kt < 4; ++kt) {
                    int ktg = w * 8 + p * 4 + kt;
                    short8v bh = EMBf[((ktg * 4 + c) * 2) * 64 + lane];
#pragma unroll
                    for (int rt = 0; rt < 4; ++rt)
                        vacc[kt][rt] = __builtin_amdgcn_mfma_f32_16x16x32_bf16(ah[rt], bh, vacc[kt][rt], 0, 0, 0);
                }
            }
            // fold into running min, then DISCARD vacc (no long-lived accumulators)
#pragma unroll
            for (int kt = 0; kt < 4; ++kt) {
                int k = (w * 8 + p * 4 + kt) * 16 + lc;
                float ek = E2S[k];
#pragma unroll
                for (int rt = 0; rt < 4; ++rt)
#pragma unroll
                    for (int reg = 0; reg < 4; ++reg)
                        v1[rt][reg] = fminf(v1[rt][reg], ek - 2.f * vacc[kt][rt][reg]);
            }
        }
        // lane-merge min across the 16 lc lanes
#pragma unroll
        for (int m = 1; m < 16; m <<= 1)
#pragma unroll
            for (int rt = 0; rt < 4; ++rt)
#pragma unroll
                for (int reg = 0; reg < 4; ++reg)
                    v1[rt][reg] = fminf(v1[rt][reg], __shfl_xor(v1[rt][reg], m));
        if (lc == 0) {
#pragma unroll
            for (int rt = 0; rt < 4; ++rt)
#pragma unroll
                for (int reg = 0; reg < 4; ++reg)
                    WMIN[w][rt * 16 + lg * 4 + reg] = v1[rt][reg];
        }
        __syncthreads();
        if (t < 64) {
            float cm = fminf(fminf(WMIN[0][t], WMIN[1][t]), fminf(WMIN[2][t], WMIN[3][t]));
            float e2r = ENC2W[0 * 64 + t] + ENC2W[1 * 64 + t] +
                        ENC2W[2 * 64 + t] + ENC2W[3 * 64 + t];
            ENC2F[t] = e2r;
            // rigorous window: 2*CauchySchwarz(coarse-vs-exact) + margin slack,
            // E <= 1.0e-4 * ||enc||  ->  window = 2.2e-4*sqrt(enc2) + 2e-6
            CMIN[t] = cm + 2.2e-4f * sqrtf(e2r) + 2e-6f;
        }
        __syncthreads();

        // ---- sweep B: recompute coarse dd, collect candidates within window ----
        for (int p = 0; p < 2; ++p) {
            f32x4 vacc[4][4];
#pragma unroll
            for (int kt = 0; kt < 4; ++kt)
#pragma unroll
                for (int rt = 0; rt < 4; ++rt)
                    vacc[kt][rt] = (f32x4){0.f, 0.f, 0.f, 0.f};
            for (int c = 0; c < 4; ++c) {
                const int aoff = c * 32 + lg * 8;
                short8v ah[4];
#pragma unroll
                for (int rt = 0; rt < 4; ++rt)
                    ah[rt] = *(const short8v*)&HH[(rt * 16 + lc) * 264 + aoff];
#pragma unroll
                for (int kt = 0; kt < 4; ++kt) {
                    int ktg = w * 8 + p * 4 + kt;
                    short8v bh = EMBf[((ktg * 4 + c) * 2) * 64 + lane];
#pragma unroll
                    for (int rt = 0; rt < 4; ++rt)
                        vacc[kt][rt] = __builtin_amdgcn_mfma_f32_16x16x32_bf16(ah[rt], bh, vacc[kt][rt], 0, 0, 0);
                }
            }
#pragma unroll
            for (int kt = 0; kt < 4; ++kt) {
                int k = (w * 8 + p * 4 + kt) * 16 + lc;
                float ek = E2S[k];
#pragma unroll
                for (int rt = 0; rt < 4; ++rt)
#pragma unroll
                    for (int reg = 0; reg < 4; ++reg) {
                        int row = rt * 16 + lg * 4 + reg;
                        float dd = ek - 2.f * vacc[kt][rt][reg];
                        if (!(dd > CMIN[row]))  // NaN-safe: NaN -> candidate
                            atomicOr(&CAND[row * 16 + (k >> 5)], 1u << (k & 31));
                    }
            }
        }
    }
    __syncthreads();

    // ---- VQ stage 2: wave-parallel exact fp32 rescore (4 lanes per row) ----
    {
        const int row = w * 16 + lc;   // wave w owns rows w*16 .. w*16+15
        float v1 = 1e30f, v2 = 1e30f; int k1 = 0;
#pragma unroll
        for (int wi = 0; wi < 4; ++wi) {
            int wd = lg * 4 + wi;      // 4 lanes split the 16 words
            unsigned int m = CAND[row * 16 + wd];
            while (m) {
                int b = __ffs(m) - 1; m &= m - 1;
                int k = wd * 32 + b;
                const float* ek = emb + (size_t)k * 128;
                float s0 = 0.f, s1 = 0.f;
#pragma unroll 8
                for (int d = 0; d < 128; d += 2) {
                    unsigned hh2 = *(const unsigned*)&HH[row * 264 + d];
                    unsigned hl2 = *(const unsigned*)&HL[row * 264 + d];
                    float e0 = __uint_as_float(hh2 << 16) + __uint_as_float(hl2 << 16);
                    float e1 = __uint_as_float(hh2 & 0xffff0000u) + __uint_as_float(hl2 & 0xffff0000u);
                    s0 += e0 * ek[d];
                    s1 += e1 * ek[d + 1];
                }
                float dd = E2S[k] - 2.f * (s0 + s1);
                if (dd < v1) { v2 = v1; v1 = dd; k1 = k; }
                else if (dd < v2) v2 = dd;
            }
        }
        // merge the 4 sub-lanes (xor 16, 32) with smaller-k tie-break
#pragma unroll
        for (int m2 = 16; m2 <= 32; m2 <<= 1) {
            float ov1 = __shfl_xor(v1, m2);
            int ok1 = __shfl_xor(k1, m2);
            float ov2 = __shfl_xor(v2, m2);
            if (ov1 < v1 || (ov1 == v1 && ok1 < k1)) {
                v2 = fminf(v1, ov2);
                v1 = ov1; k1 = ok1;
            } else {
                v2 = fminf(v2, ov1);
            }
        }
        if (lg == 0) {
            int flag = (v2 - v1 >= MARGINF) ? 0 : 1;  // NaN-safe
            IDXR[row] = k1;
            FLAGR[row] = flag;
            int grow = row0 + row;
            if (flag)
                atomicOr((unsigned int*)ws + WS_MASK + (grow >> 5), 1u << (grow & 31));
            out[grow] = (float)k1;
            if (!flag) lvq = ENC2F[row] + v1;
        }
    }
    __syncthreads();

    // ---- gather q (exact fp32), write q_st, hi-only split for decoder ----
    {
        int d = t & 127, rhalf = t >> 7;
#pragma unroll
        for (int e = 0; e < 32; ++e) {
            int r = (e << 1) | rhalf;
            int k1 = IDXR[r];
            float q = emb[(size_t)k1 * 128 + d];
            out[NB + (size_t)(row0 + r) * 128 + d] = q;
            HH[r * 264 + d] = bf16rn(q);
        }
    }

    // ---- decoder (hi-only, 1-term) ----
    mfma_mlp4<4, 4, true, false, 1, false>(D1f, d1b, HH, HL, ENC2W, w, lane);
    mfma_mlp4<4, 8, true, false, 1, false>(D2f, d2b, HH, HL, ENC2W, w, lane);
    __syncthreads();  // dec2 hi ready

    // ---- rec: wave w handles rows w*16..+15 via MFMA (hi-only) ----
    {
        f32x4 racc = (f32x4){0.f, 0.f, 0.f, 0.f};
        for (int c = 0; c < 8; ++c) {
            const int boff = c * 32 + lg * 8;
            short8v bh = *(const short8v*)&HH[(w * 16 + lc) * 264 + boff];
            int fi = (c * 2) * 64 + lane;
            short8v ah = RWf[fi];
            racc = __builtin_amdgcn_mfma_f32_16x16x32_bf16(ah, bh, racc, 0, 0, 0);
        }
        int r = w * 16 + lc;
#pragma unroll
        for (int reg = 0; reg < 4; ++reg) {
            int j = lg * 4 + reg;
            if (j < 6) {
                float rec = tanhf(racc[reg] + rb[j]);
                float df = rec - AT[r * 6 + j];
                if (!FLAGR[r]) lrec += df * df;
            }
        }
    }

    // ---- block loss reduction -> hashed fp64 slots ----
#pragma unroll
    for (int m = 1; m < 64; m <<= 1) {
        lvq += __shfl_xor(lvq, m);
        lrec += __shfl_xor(lrec, m);
    }
    if ((t & 63) == 0) { RED[t >> 6] = lvq; RED[4 + (t >> 6)] = lrec; }
    __syncthreads();
    if (t == 0) {
        int slot = blockIdx.x & 63;
        atomicAdd((double*)ws + slot, (double)((RED[0] + RED[1]) + (RED[2] + RED[3])));
        atomicAdd((double*)ws + 64 + slot, (double)((RED[4] + RED[5]) + (RED[6] + RED[7])));
    }
}

// ---------------- fp64 repair of ambiguous rows (256 blocks, stride over words) ----------------
__global__ __launch_bounds__(256) void vqvae_fix(
    const float* __restrict__ action,
    const float* __restrict__ w1, const float* __restrict__ b1,
    const float* __restrict__ w2, const float* __restrict__ b2,
    const float* __restrict__ w3, const float* __restrict__ b3,
    const float* __restrict__ emb,
    const float* __restrict__ d1w, const float* __restrict__ d1b,
    const float* __restrict__ d2w, const float* __restrict__ d2b,
    const float* __restrict__ rw, const float* __restrict__ rb,
    float* __restrict__ out, float* __restrict__ ws)
{
    __shared__ double H1[256];
    __shared__ double H2[256];
    __shared__ double ENC[128];
    __shared__ double QD[128];
    __shared__ double SRED[256];
    __shared__ int SK[256];
    __shared__ double SA[6];

    const int t = threadIdx.x;

    for (int widx = blockIdx.x; widx < WS_MASKW; widx += gridDim.x) {
        const unsigned int word = ((const unsigned int*)ws)[WS_MASK + widx];
        if (word == 0u) continue;  // uniform across block

        for (int bit = 0; bit < 32; ++bit) {
            if (!(word & (1u << bit))) continue;
            const int row = (widx << 5) + bit;

            if (t < 6) SA[t] = (double)action[(size_t)row * 6 + t];
            __syncthreads();
            {
                double a = (double)b1[t];
#pragma unroll
                for (int i = 0; i < 6; ++i) a += (double)w1[t * 6 + i] * SA[i];
                H1[t] = a > 0.0 ? a : 0.0;
            }
            __syncthreads();
            {
                const float* w = w2 + (size_t)t * 256;
                double a0 = 0, a1 = 0, a2 = 0, a3 = 0;
                for (int i = 0; i < 256; i += 4) {
                    a0 += (double)w[i] * H1[i];     a1 += (double)w[i + 1] * H1[i + 1];
                    a2 += (double)w[i + 2] * H1[i + 2]; a3 += (double)w[i + 3] * H1[i + 3];
                }
                double a = (double)b2[t] + a0 + a1 + a2 + a3;
                H2[t] = a > 0.0 ? a : 0.0;
            }
            __syncthreads();
            if (t < 128) {
                const float* w = w3 + (size_t)t * 256;
                double a0 = 0, a1 = 0, a2 = 0, a3 = 0;
                for (int i = 0; i < 256; i += 4) {
                    a0 += (double)w[i] * H2[i];     a1 += (double)w[i + 1] * H2[i + 1];
                    a2 += (double)w[i + 2] * H2[i + 2]; a3 += (double)w[i + 3] * H2[i + 3];
                }
                ENC[t] = (double)b3[t] + a0 + a1 + a2 + a3;
            }
            __syncthreads();
            double best = 1e300; int bk = 0;
#pragma unroll
            for (int kk = 0; kk < 2; ++kk) {
                int k = t + kk * 256;
                const float* e = emb + (size_t)k * 128;
                double s0 = 0, s1 = 0;
                for (int d = 0; d < 128; d += 2) {
                    double df0 = ENC[d] - (double)e[d];
                    double df1 = ENC[d + 1] - (double)e[d + 1];
                    s0 += df0 * df0; s1 += df1 * df1;
                }
                double s = s0 + s1;
                if (s < best) { best = s; bk = k; }
            }
            SRED[t] = best; SK[t] = bk;
            __syncthreads();
            for (int st = 128; st > 0; st >>= 1) {
                if (t < st) {
                    double ov = SRED[t + st]; int ok = SK[t + st];
                    if (ov < SRED[t] || (ov == SRED[t] && ok < SK[t])) { SRED[t] = ov; SK[t] = ok; }
                }
                __syncthreads();
            }
            const int bestk = SK[0];
            double lv = 0.0;
            if (t < 128) {
                double q = (double)emb[(size_t)bestk * 128 + t];
                QD[t] = q;
                double df = ENC[t] - q;
                lv = df * df;
                out[NB + (size_t)row * 128 + t] = (float)q;
            }
            if (t == 0) out[row] = (float)bestk;
            __syncthreads();
            {
                const float* w = d1w + (size_t)t * 128;
                double a0 = 0, a1 = 0;
                for (int i = 0; i < 128; i += 2) {
                    a0 += (double)w[i] * QD[i]; a1 += (double)w[i + 1] * QD[i + 1];
                }
                double a = (double)d1b[t] + a0 + a1;
                H1[t] = a > 0.0 ? a : 0.0;
            }
            __syncthreads();
            {
                const float* w = d2w + (size_t)t * 256;
                double a0 = 0, a1 = 0, a2 = 0, a3 = 0;
                for (int i = 0; i < 256; i += 4) {
                    a0 += (double)w[i] * H1[i];     a1 += (double)w[i + 1] * H1[i + 1];
                    a2 += (double)w[i + 2] * H1[i + 2]; a3 += (double)w[i + 3] * H1[i + 3];
                }
                double a = (double)d2b[t] + a0 + a1 + a2 + a3;
                H2[t] = a > 0.0 ? a : 0.0;
            }
            __syncthreads();
            double lr = 0.0;
            if (t < 6) {
                const float* w = rw + (size_t)t * 256;
                double a0 = 0, a1 = 0;
                for (int i = 0; i < 256; i += 2) {
                    a0 += (double)w[i] * H2[i]; a1 += (double)w[i + 1] * H2[i + 1];
                }
                double rec = tanh((double)rb[t] + a0 + a1);
                double df = rec - SA[t];
                lr = df * df;
            }
            SRED[t] = lv;
            __syncthreads();
            for (int st = 128; st > 0; st >>= 1) {
                if (t < st) SRED[t] += SRED[t + st];
                __syncthreads();
            }
            if (t == 0) atomicAdd((double*)ws + 0, SRED[0]);
            if (t < 6) atomicAdd((double*)ws + 64, lr);
            __syncthreads();
        }
    }
}

__global__ void vqvae_fin(const float* __restrict__ ws, float* __restrict__ out) {
    if (threadIdx.x == 0 && blockIdx.x == 0) {
        const double* D = (const double*)ws;
        double sv = 0.0, sr = 0.0;
        for (int i = 0; i < 64; ++i) { sv += D[i]; sr += D[64 + i]; }
        double loss = sr / ((double)NB * 6.0) + 1.25 * (sv / ((double)NB * 128.0));
        out[(size_t)NB * 129] = (float)loss;
    }
}

// ---------------- fp32 fallback (only if ws too small for splits) ----------------
static __device__ __forceinline__ void gemm_out256(
    const float* __restrict__ W, const float* __restrict__ bias, int IN,
    const float* __restrict__ hin, float* __restrict__ hout,
    float* __restrict__ WC, int t, int tx, int r0, bool do_relu)
{
    float acc[2][4][4];
#pragma unroll
    for (int g = 0; g < 2; ++g)
#pragma unroll
        for (int a = 0; a < 4; ++a)
#pragma unroll
            for (int b = 0; b < 4; ++b) acc[g][a][b] = 0.f;
    float4 pa = *(const float4*)(W + (size_t)t * IN);
    float4 pb = *(const float4*)(W + (size_t)t * IN + 4);
    for (int i0 = 0; i0 < IN; i0 += 8) {
        __syncthreads();
        WC[0 * 256 + t] = pa.x; WC[1 * 256 + t] = pa.y;
        WC[2 * 256 + t] = pa.z; WC[3 * 256 + t] = pa.w;
        WC[4 * 256 + t] = pb.x; WC[5 * 256 + t] = pb.y;
        WC[6 * 256 + t] = pb.z; WC[7 * 256 + t] = pb.w;
        __syncthreads();
        if (i0 + 8 < IN) {
            pa = *(const float4*)(W + (size_t)t * IN + i0 + 8);
            pb = *(const float4*)(W + (size_t)t * IN + i0 + 12);
        }
#pragma unroll
        for (int i = 0; i < 8; ++i) {
            int row = i0 + i;
            float4 h = *(const float4*)&hin[row * 32 + (r0 ^ SWC(row))];
            float4 w0 = *(const float4*)&WC[i * 256 + 4 * tx];
            float4 w1v = *(const float4*)&WC[i * 256 + 128 + 4 * tx];
            float wv0[4] = {w0.x, w0.y, w0.z, w0.w};
            float wv1[4] = {w1v.x, w1v.y, w1v.z, w1v.w};
            float hv[4] = {h.x, h.y, h.z, h.w};
#pragma unroll
            for (int a = 0; a < 4; ++a)
#pragma unroll
                for (int b = 0; b < 4; ++b) {
                    acc[0][a][b] += wv0[a] * hv[b];
                    acc[1][a][b] += wv1[a] * hv[b];
                }
        }
    }
#pragma unroll
    for (int g = 0; g < 2; ++g)
#pragma unroll
        for (int a = 0; a < 4; ++a) {
            int j = g * 128 + 4 * tx + a;
            float bj = bias[j];
            float4 v;
            v.x = acc[g][a][0] + bj; v.y = acc[g][a][1] + bj;
            v.z = acc[g][a][2] + bj; v.w = acc[g][a][3] + bj;
            if (do_relu) {
                v.x = fmaxf(v.x, 0.f); v.y = fmaxf(v.y, 0.f);
                v.z = fmaxf(v.z, 0.f); v.w = fmaxf(v.w, 0.f);
            }
            *(float4*)&hout[j * 32 + (r0 ^ SWC(j))] = v;
        }
    __syncthreads();
}

__global__ __launch_bounds__(256, 2) void vqvae_main_fp32(
    const float* __restrict__ action,
    const float* __restrict__ w1, const float* __restrict__ b1,
    const float* __restrict__ w2, const float* __restrict__ b2,
    const float* __restrict__ w3, const float* __restrict__ b3,
    const float* __restrict__ emb,
    const float* __restrict__ d1w, const float* __restrict__ d1b,
    const float* __restrict__ d2w, const float* __restrict__ d2b,
    const float* __restrict__ rw, const float* __restrict__ rb,
    float* __restrict__ out, float* __restrict__ ws)
{
    __shared__ float X[256 * 32];
    __shared__ float Y[256 * 32];
    __shared__ float WC[2048];
    __shared__ float AT[6 * 32];
    __shared__ int IDXR[32];
    __shared__ int FLAGR[32];
    __shared__ float RED[8];

    const int t = threadIdx.x;
    const int tx = t & 31, ty = t >> 5;
    const int r0 = ty * 4;
    const int row0 = blockIdx.x * 32;

    if (t < 192) {
        int r = t / 6, i = t - r * 6;
        AT[i * 32 + r] = action[(size_t)row0 * 6 + t];
    }
    __syncthreads();
    {
#pragma unroll
        for (int i = 0; i < 6; ++i) WC[i * 256 + t] = w1[t * 6 + i];
        __syncthreads();
        float acc[2][4][4];
#pragma unroll
        for (int g = 0; g < 2; ++g)
#pragma unroll
            for (int a = 0; a < 4; ++a)
#pragma unroll
                for (int b = 0; b < 4; ++b) acc[g][a][b] = 0.f;
#pragma unroll
        for (int i = 0; i < 6; ++i) {
            float4 h = *(const float4*)&AT[i * 32 + r0];
            float4 w0 = *(const float4*)&WC[i * 256 + 4 * tx];
            float4 w1v = *(const float4*)&WC[i * 256 + 128 + 4 * tx];
            float wv0[4] = {w0.x, w0.y, w0.z, w0.w};
            float wv1[4] = {w1v.x, w1v.y, w1v.z, w1v.w};
            float hv[4] = {h.x, h.y, h.z, h.w};
#pragma unroll
            for (int a = 0; a < 4; ++a)
#pragma unroll
                for (int b = 0; b < 4; ++b) {
                    acc[0][a][b] += wv0[a] * hv[b];
                    acc[1][a][b] += wv1[a] * hv[b];
                }
        }
#pragma unroll
        for (int g = 0; g < 2; ++g)
#pragma unroll
            for (int a = 0; a < 4; ++a) {
                int j = g * 128 + 4 * tx + a;
                float bj = b1[j];
                float4 v;
                v.x = fmaxf(acc[g][a][0] + bj, 0.f);
                v.y = fmaxf(acc[g][a][1] + bj, 0.f);
                v.z = fmaxf(acc[g][a][2] + bj, 0.f);
                v.w = fmaxf(acc[g][a][3] + bj, 0.f);
                *(float4*)&X[j * 32 + (r0 ^ SWC(j))] = v;
            }
        __syncthreads();
    }
    gemm_out256(w2, b2, 256, X, Y, WC, t, tx, r0, true);
    {
        float acc[4][4];
#pragma unroll
        for (int a = 0; a < 4; ++a)
#pragma unroll
            for (int b = 0; b < 4; ++b) acc[a][b] = 0.f;
        float4 pa, pb;
        if (t < 128) {
            pa = *(const float4*)(w3 + (size_t)t * 256);
            pb = *(const float4*)(w3 + (size_t)t * 256 + 4);
        }
        for (int i0 = 0; i0 < 256; i0 += 8) {
            __syncthreads();
            if (t < 128) {
                WC[0 * 128 + t] = pa.x; WC[1 * 128 + t] = pa.y;
                WC[2 * 128 + t] = pa.z; WC[3 * 128 + t] = pa.w;
                WC[4 * 128 + t] = pb.x; WC[5 * 128 + t] = pb.y;
                WC[6 * 128 + t] = pb.z; WC[7 * 128 + t] = pb.w;
            }
            __syncthreads();
            if (t < 128 && i0 + 8 < 256) {
                pa = *(const float4*)(w3 + (size_t)t * 256 + i0 + 8);
                pb = *(const float4*)(w3 + (size_t)t * 256 + i0 + 12);
            }
#pragma unroll
            for (int i = 0; i < 8; ++i) {
                int row = i0 + i;
                float4 h = *(const float4*)&Y[row * 32 + (r0 ^ SWC(row))];
                float4 w0 = *(const float4*)&WC[i * 128 + 4 * tx];
                float wv[4] = {w0.x, w0.y, w0.z, w0.w};
                float hv[4] = {h.x, h.y, h.z, h.w};
#pragma unroll
                for (int a = 0; a < 4; ++a)
#pragma unroll
                    for (int b = 0; b < 4; ++b) acc[a][b] += wv[a] * hv[b];
            }
        }
#pragma unroll
        for (int a = 0; a < 4; ++a) {
            int j = 4 * tx + a;
            float bj = b3[j];
            float4 v;
            v.x = acc[a][0] + bj; v.y = acc[a][1] + bj;
            v.z = acc[a][2] + bj; v.w = acc[a][3] + bj;
            *(float4*)&X[j * 32 + (r0 ^ SWC(j))] = v;
        }
        __syncthreads();
    }
    {
        float bv1[4], bv2[4];
        int bk1[4];
        float acc[4][4][4];
#pragma unroll
        for (int p = 0; p < 4; ++p)
#pragma unroll
            for (int a = 0; a < 4; ++a)
#pragma unroll
                for (int b = 0; b < 4; ++b) acc[p][a][b] = 0.f;
        float4 qa = *(const float4*)(emb + (size_t)t * 128);
        float4 qb = *(const float4*)(emb + (size_t)(t + 256) * 128);
        for (int d0 = 0; d0 < 128; d0 += 4) {
            __syncthreads();
            WC[0 * 512 + t] = qa.x; WC[1 * 512 + t] = qa.y;
            WC[2 * 512 + t] = qa.z; WC[3 * 512 + t] = qa.w;
            WC[0 * 512 + 256 + t] = qb.x; WC[1 * 512 + 256 + t] = qb.y;
            WC[2 * 512 + 256 + t] = qb.z; WC[3 * 512 + 256 + t] = qb.w;
            __syncthreads();
            if (d0 + 4 < 128) {
                qa = *(const float4*)(emb + (size_t)t * 128 + d0 + 4);
                qb = *(const float4*)(emb + (size_t)(t + 256) * 128 + d0 + 4);
            }
#pragma unroll
            for (int i = 0; i < 4; ++i) {
                int row = d0 + i;
                float4 h = *(const float4*)&X[row * 32 + (r0 ^ SWC(row))];
                float hv[4] = {h.x, h.y, h.z, h.w};
#pragma unroll
                for (int p = 0; p < 4; ++p) {
                    float4 w0 = *(const float4*)&WC[i * 512 + p * 128 + 4 * tx];
                    float wv[4] = {w0.x, w0.y, w0.z, w0.w};
#pragma unroll
                    for (int a = 0; a < 4; ++a)
#pragma unroll
                        for (int b = 0; b < 4; ++b) acc[p][a][b] += wv[a] * hv[b];
                }
            }
        }
#pragma unroll
        for (int b = 0; b < 4; ++b) { bv1[b] = 1e30f; bv2[b] = 1e30f; bk1[b] = 0; }
#pragma unroll
        for (int p = 0; p < 4; ++p)
#pragma unroll
            for (int a = 0; a < 4; ++a) {
                int k = p * 128 + 4 * tx + a;
                float ek = ws[WS_E2 + k];
#pragma unroll
                for (int b = 0; b < 4; ++b) {
                    float dd = ek - 2.f * acc[p][a][b];
                    if (dd < bv1[b]) { bv2[b] = bv1[b]; bv1[b] = dd; bk1[b] = k; }
                    else if (dd < bv2[b]) bv2[b] = dd;
                }
            }
#pragma unroll
        for (int m = 1; m < 32; m <<= 1) {
#pragma unroll
            for (int b = 0; b < 4; ++b) {
                float ov1 = __shfl_xor(bv1[b], m);
                int ok1 = __shfl_xor(bk1[b], m);
                float ov2 = __shfl_xor(bv2[b], m);
                if (ov1 < bv1[b] || (ov1 == bv1[b] && ok1 < bk1[b])) {
                    bv2[b] = fminf(bv1[b], ov2);
                    bv1[b] = ov1; bk1[b] = ok1;
                } else {
                    bv2[b] = fminf(bv2[b], ov1);
                }
            }
        }
        if (tx == 0) {
#pragma unroll
            for (int b = 0; b < 4; ++b) {
                IDXR[r0 + b] = bk1[b];
                FLAGR[r0 + b] = (bv2[b] - bv1[b] >= MARGINF) ? 0 : 1;
            }
        }
    }
    __syncthreads();
    if (t < 32) {
        int row = row0 + t;
        if (FLAGR[t])
            atomicOr((unsigned int*)ws + WS_MASK + (row >> 5), 1u << (row & 31));
        out[row] = (float)IDXR[t];
    }
    float lvq = 0.f, lrec = 0.f;
    {
        int d = t & 127, rq = t >> 7;
        int cd = SWC(d);
#pragma unroll
        for (int e = 0; e < 4; ++e) {
            int rr = (rq + 2 * e) * 4;
            float4 en = *(const float4*)&X[d * 32 + (rr ^ cd)];
            float q0 = emb[(size_t)IDXR[rr + 0] * 128 + d];
            float q1 = emb[(size_t)IDXR[rr + 1] * 128 + d];
            float q2 = emb[(size_t)IDXR[rr + 2] * 128 + d];
            float q3 = emb[(size_t)IDXR[rr + 3] * 128 + d];
            float4 qv; qv.x = q0; qv.y = q1; qv.z = q2; qv.w = q3;
            *(float4*)&X[(128 + d) * 32 + (rr ^ cd)] = qv;
            if (!FLAGR[rr + 0]) lvq += (en.x - q0) * (en.x - q0);
            if (!FLAGR[rr + 1]) lvq += (en.y - q1) * (en.y - q1);
            if (!FLAGR[rr + 2]) lvq += (en.z - q2) * (en.z - q2);
            if (!FLAGR[rr + 3]) lvq += (en.w - q3) * (en.w - q3);
            out[NB + (size_t)(row0 + rr + 0) * 128 + d] = q0;
            out[NB + (size_t)(row0 + rr + 1) * 128 + d] = q1;
            out[NB + (size_t)(row0 + rr + 2) * 128 + d] = q2;
            out[NB + (size_t)(row0 + rr + 3) * 128 + d] = q3;
        }
    }
    __syncthreads();
    gemm_out256(d1w, d1b, 128, X + 128 * 32, Y, WC, t, tx, r0, true);
    gemm_out256(d2w, d2b, 256, Y, X, WC, t, tx, r0, true);
    if (t < 192) {
        int jj = t >> 5, r = t & 31;
        const float* wr = rw + jj * 256;
        float a0 = 0.f, a1 = 0.f, a2 = 0.f, a3 = 0.f;
        for (int i = 0; i < 256; i += 4) {
            a0 += wr[i] * X[i * 32 + (r ^ SWC(i))];
            a1 += wr[i + 1] * X[(i + 1) * 32 + (r ^ SWC(i + 1))];
            a2 += wr[i + 2] * X[(i + 2) * 32 + (r ^ SWC(i + 2))];
            a3 += wr[i + 3] * X[(i + 3) * 32 + (r ^ SWC(i + 3))];
        }
        float rec = tanhf(rb[jj] + (a0 + a1) + (a2 + a3));
        float df = rec - AT[jj * 32 + r];
        if (!FLAGR[r]) lrec = df * df;
    }
#pragma unroll
    for (int m = 1; m < 64; m <<= 1) {
        lvq += __shfl_xor(lvq, m);
        lrec += __shfl_xor(lrec, m);
    }
    if ((t & 63) == 0) { RED[t >> 6] = lvq; RED[4 + (t >> 6)] = lrec; }
    __syncthreads();
    if (t == 0) {
        int slot = blockIdx.x & 63;
        atomicAdd((double*)ws + slot, (double)((RED[0] + RED[1]) + (RED[2] + RED[3])));
        atomicAdd((double*)ws + 64 + slot, (double)((RED[4] + RED[5]) + (RED[6] + RED[7])));
    }
}

extern "C" void kernel_launch(void* const* d_in, const int* in_sizes, int n_in,
                              void* d_out, int out_size, void* d_ws, size_t ws_size,
                              hipStream_t stream) {
    const float* action = (const float*)d_in[0];
    const float* w1 = (const float*)d_in[1];
    const float* b1 = (const float*)d_in[2];
    const float* w2 = (const float*)d_in[3];
    const float* b2 = (const float*)d_in[4];
    const float* w3 = (const float*)d_in[5];
    const float* b3 = (const float*)d_in[6];
    const float* emb = (const float*)d_in[7];
    const float* d1w = (const float*)d_in[8];
    const float* d1b = (const float*)d_in[9];
    const float* d2w = (const float*)d_in[10];
    const float* d2b = (const float*)d_in[11];
    const float* rw = (const float*)d_in[12];
    const float* rb = (const float*)d_in[13];
    float* out = (float*)d_out;
    float* ws = (float*)d_ws;

    const size_t need_mfma = (size_t)WS_BASE_BYTES + (size_t)SPLIT_TOTAL * 2;
    const int use_mfma = (ws_size >= need_mfma) ? 1 : 0;
    const int dyn_lds = 64 * 264 * 2 * 2;  // 67584 B

    prep_kernel<<<1043, 256, 0, stream>>>(w1, w2, w3, emb, d1w, d2w, rw, ws, use_mfma);
    if (use_mfma) {
        hipFuncSetAttribute((const void*)vqvae_main_mfma,
                            hipFuncAttributeMaxDynamicSharedMemorySize, dyn_lds);
        vqvae_main_mfma<<<NB / 64, 256, dyn_lds, stream>>>(action, b1, b2, b3, emb,
                                                           d1b, d2b, rb, out, ws);
    } else {
        vqvae_main_fp32<<<NB / 32, 256, 0, stream>>>(action, w1, b1, w2, b2, w3, b3, emb,
                                                     d1w, d1b, d2w, d2b, rw, rb, out, ws);
    }
    vqvae_fix<<<256, 256, 0, stream>>>(action, w1, b1, w2, b2, w3, b3, emb,
                                       d1w, d1b, d2w, d2b, rw, rb, out, ws);
    vqvae_fin<<<1, 64, 0, stream>>>(ws, out);
}